// Round 6
// baseline (330.080 us; speedup 1.0000x reference)
//
#include <hip/hip_runtime.h>
#include <math.h>

#define BB 4
#define NN 2048
#define MM 2048
#define HEADS 8
#define DH 64

typedef _Float16 f16;
typedef _Float16 f16x2 __attribute__((ext_vector_type(2)));
typedef _Float16 f16x4 __attribute__((ext_vector_type(4)));
typedef _Float16 f16x8 __attribute__((ext_vector_type(8)));
typedef float f32x4 __attribute__((ext_vector_type(4)));
typedef short bf16x8v __attribute__((ext_vector_type(8)));
typedef unsigned short ushort;

#define LOG2E 1.44269504088896f
#define QSCALE (0.125f * LOG2E)

#if __has_builtin(__builtin_amdgcn_exp2f)
#define EXP2(x) __builtin_amdgcn_exp2f(x)
#else
#define EXP2(x) exp2f(x)
#endif

__device__ __forceinline__ void bsplit(float v, ushort& h, ushort& l) {
    unsigned bits = __float_as_uint(v);
    float res = v - __uint_as_float(bits & 0xffff0000u);
    h = (ushort)(bits >> 16);
    l = (ushort)(__float_as_uint(res) >> 16);
}

__device__ __forceinline__ f16x4 pk4(float a, float b, float c, float d) {
#if __has_builtin(__builtin_amdgcn_cvt_pkrtz)
    auto t0 = __builtin_amdgcn_cvt_pkrtz(a, b);
    auto t1 = __builtin_amdgcn_cvt_pkrtz(c, d);
    f16x4 r;
    r[0] = t0[0]; r[1] = t0[1]; r[2] = t1[0]; r[3] = t1[1];
    return r;
#else
    f16x4 r = {(f16)a, (f16)b, (f16)c, (f16)d};
    return r;
#endif
}

// ---------------------------------------------------------------------------
// W [K][N] fp32 -> [N][K] bf16 hi/lo (for Wo, final bf16x2 GEMM)
// ---------------------------------------------------------------------------
__global__ void wsplit_k(const float* __restrict__ W, ushort* __restrict__ Th,
                         ushort* __restrict__ Tl, int K, int N)
{
    __shared__ ushort Sh[64][36], Sl[64][36];
    const int tid = threadIdx.x;
    const int k0 = blockIdx.x * 32, n0 = blockIdx.y * 64;
    const int kr = tid >> 3, nc = (tid & 7) * 8;
    float4 v0 = *(const float4*)(W + (size_t)(k0 + kr) * N + n0 + nc);
    float4 v1 = *(const float4*)(W + (size_t)(k0 + kr) * N + n0 + nc + 4);
    float e[8] = {v0.x, v0.y, v0.z, v0.w, v1.x, v1.y, v1.z, v1.w};
#pragma unroll
    for (int j = 0; j < 8; j++) {
        ushort h, l;
        bsplit(e[j], h, l);
        Sh[nc + j][kr] = h;
        Sl[nc + j][kr] = l;
    }
    __syncthreads();
    const int n = tid >> 2, kc = (tid & 3) * 8;
    *(uint4*)(Th + (size_t)(n0 + n) * K + k0 + kc) = *(const uint4*)(&Sh[n][kc]);
    *(uint4*)(Tl + (size_t)(n0 + n) * K + k0 + kc) = *(const uint4*)(&Sl[n][kc]);
}

// ---------------------------------------------------------------------------
// W [K][N] fp32 -> [N][K] f16 (for Wq, Wkv single-f16 GEMMs)
// ---------------------------------------------------------------------------
__global__ void wtrans_k(const float* __restrict__ W, f16* __restrict__ T16,
                         int K, int N)
{
    __shared__ f16 Sh[64][36];
    const int tid = threadIdx.x;
    const int k0 = blockIdx.x * 32, n0 = blockIdx.y * 64;
    const int kr = tid >> 3, nc = (tid & 7) * 8;
    float4 v0 = *(const float4*)(W + (size_t)(k0 + kr) * N + n0 + nc);
    float4 v1 = *(const float4*)(W + (size_t)(k0 + kr) * N + n0 + nc + 4);
    float e[8] = {v0.x, v0.y, v0.z, v0.w, v1.x, v1.y, v1.z, v1.w};
#pragma unroll
    for (int j = 0; j < 8; j++) Sh[nc + j][kr] = (f16)e[j];
    __syncthreads();
    const int n = tid >> 2, kc = (tid & 3) * 8;
    *(uint4*)(T16 + (size_t)(n0 + n) * K + k0 + kc) = *(const uint4*)(&Sh[n][kc]);
}

// ---------------------------------------------------------------------------
// Single-f16 MFMA GEMM: C = A(fp32, cvt in staging) @ Bt^T(f16 [N][K]).
// Tile 128x64, 4 waves (wave 32r x 64c), BK=32, 1 MFMA per sub-tile.
// MODE 0: qws f16 = tanh(acc)*0.125*log2e  (pre-scaled for exp2 softmax)
// MODE 1: by<8: kws f16 = tanh(acc); by>=8: vt f16 [bh][d][m] = acc
// ---------------------------------------------------------------------------
template<int MODE>
__launch_bounds__(256)
__global__ void fgemm(const float* __restrict__ A, const f16* __restrict__ Bt,
                      f16* __restrict__ o16a, f16* __restrict__ o16b, int K)
{
    __shared__ f16 sA[128 * 36];
    __shared__ f16 sB[64 * 36];

    const int tid  = threadIdx.x;
    const int wave = tid >> 6, lane = tid & 63;
    const int l15  = lane & 15, quad = lane >> 4;
    const size_t r0 = (size_t)blockIdx.x * 128;
    const int c0 = blockIdx.y * 64;

    const int ar = tid >> 1;           // 0..127
    const int ac = (tid & 1) * 16;     // 0 / 16
    const int br = tid >> 2;           // 0..63
    const int bc = (tid & 3) * 8;

    f32x4 acc[2][4] = {};

    for (int k0 = 0; k0 < K; k0 += 32) {
        const float* ap = A + (r0 + ar) * K + k0 + ac;
        float4 a0 = *(const float4*)(ap + 0);
        float4 a1 = *(const float4*)(ap + 4);
        float4 a2 = *(const float4*)(ap + 8);
        float4 a3 = *(const float4*)(ap + 12);
        uint4  bv = *(const uint4*)(Bt + (size_t)(c0 + br) * K + k0 + bc);
        f16x8 pa0, pa1;
        pa0[0] = (f16)a0.x; pa0[1] = (f16)a0.y; pa0[2] = (f16)a0.z; pa0[3] = (f16)a0.w;
        pa0[4] = (f16)a1.x; pa0[5] = (f16)a1.y; pa0[6] = (f16)a1.z; pa0[7] = (f16)a1.w;
        pa1[0] = (f16)a2.x; pa1[1] = (f16)a2.y; pa1[2] = (f16)a2.z; pa1[3] = (f16)a2.w;
        pa1[4] = (f16)a3.x; pa1[5] = (f16)a3.y; pa1[6] = (f16)a3.z; pa1[7] = (f16)a3.w;
        __syncthreads();
        *(f16x8*)(sA + ar * 36 + ac)     = pa0;
        *(f16x8*)(sA + ar * 36 + ac + 8) = pa1;
        *(uint4*)(sB + br * 36 + bc)     = bv;
        __syncthreads();

        f16x8 a[2], b[4];
#pragma unroll
        for (int rt = 0; rt < 2; rt++)
            a[rt] = *(const f16x8*)(sA + (wave * 32 + rt * 16 + l15) * 36 + quad * 8);
#pragma unroll
        for (int ct = 0; ct < 4; ct++)
            b[ct] = *(const f16x8*)(sB + (ct * 16 + l15) * 36 + quad * 8);
#pragma unroll
        for (int rt = 0; rt < 2; rt++)
#pragma unroll
            for (int ct = 0; ct < 4; ct++)
                acc[rt][ct] = __builtin_amdgcn_mfma_f32_16x16x32_f16(
                    a[rt], b[ct], acc[rt][ct], 0, 0, 0);
    }

    const int b    = (int)(r0 >> 11);
    const int rloc = ((int)(r0 & 2047)) + wave * 32;

#pragma unroll
    for (int rt = 0; rt < 2; rt++)
#pragma unroll
        for (int ct = 0; ct < 4; ct++) {
            if (MODE == 0 || (MODE == 1 && blockIdx.y < 8)) {
                const int h = blockIdx.y & 7;
                const int d = ct * 16 + l15;
#pragma unroll
                for (int reg = 0; reg < 4; reg++) {
                    const int n = rloc + rt * 16 + quad * 4 + reg;
                    float v = tanhf(acc[rt][ct][reg]);
                    if (MODE == 0) v *= QSCALE;
                    o16a[(((size_t)b * 8 + h) * 2048 + n) * 64 + d] = (f16)v;
                }
            } else {
                const int h = blockIdx.y - 8;
                const int d = ct * 16 + l15;
                const int m0 = rloc + rt * 16 + quad * 4;
                f16x4 pk;
#pragma unroll
                for (int reg = 0; reg < 4; reg++) pk[reg] = (f16)acc[rt][ct][reg];
                *(f16x4*)(o16b + (((size_t)b * 8 + h) * 64 + d) * 2048 + m0) = pk;
            }
        }
}

// ---------------------------------------------------------------------------
// MFMA fp16 flash attention v3.
// Softmax p = exp2(S') where S' accumulates on a C-init of {0, -1e30} (column
// mask folded into MFMA). q pre-scaled by log2e. Dead rows: Q-frag zeroed +
// C-init 0 -> p = 1 over all 2049. Row-sum via ones-column MFMA (no shuffles).
// Block = 128 thr = 2 waves; wave owns 32 q rows; j-tile 64. No P round-trip.
// ---------------------------------------------------------------------------
__launch_bounds__(128)
__global__ void attn_k(const f16* __restrict__ qws, const f16* __restrict__ kws,
                       const f16* __restrict__ vtws,
                       const int* __restrict__ mask, const int* __restrict__ cmask,
                       const float* __restrict__ nk, const float* __restrict__ nv,
                       ushort* __restrict__ oh, ushort* __restrict__ ol)
{
    __shared__ f16 sK[64 * 72];      // [j][d]
    __shared__ f16 sV[64 * 72];      // [d][j]

    const int tid  = threadIdx.x;
    const int wave = tid >> 6, lane = tid & 63;
    const int l15  = lane & 15, quad = lane >> 4;
    const int bh = blockIdx.x, b = bh >> 3, h = bh & 7;
    const int q0 = blockIdx.y * 64 + wave * 32;

    // Q fragments (pre-scaled by 0.125*log2e in fgemm<0>)
    f16x8 qf[2][2];
    const f16* qbase = qws + ((size_t)bh * NN + q0) * DH;
#pragma unroll
    for (int rt = 0; rt < 2; rt++)
#pragma unroll
        for (int ks = 0; ks < 2; ks++)
            qf[rt][ks] = *(const f16x8*)(qbase + (rt * 16 + l15) * DH + ks * 32 + quad * 8);

    // null-key logit (already log2-scaled via qf)
    float pn[2] = {0.f, 0.f};
#pragma unroll
    for (int ks = 0; ks < 2; ks++)
#pragma unroll
        for (int t = 0; t < 8; t++) {
            float nkt = tanhf(nk[ks * 32 + quad * 8 + t]);
            pn[0] += (float)qf[0][ks][t] * nkt;
            pn[1] += (float)qf[1][ks][t] * nkt;
        }
    const f16x8 zz = {(f16)0, (f16)0, (f16)0, (f16)0, (f16)0, (f16)0, (f16)0, (f16)0};
    float pnull[2], negsel[2];
#pragma unroll
    for (int rt = 0; rt < 2; rt++) {
        pn[rt] += __shfl_xor(pn[rt], 16);
        pn[rt] += __shfl_xor(pn[rt], 32);
        const int rowOk = mask[(size_t)b * NN + q0 + rt * 16 + l15];
        pnull[rt]  = rowOk ? EXP2(pn[rt]) : 1.0f;
        negsel[rt] = rowOk ? -1.0e30f : 0.0f;
        if (!rowOk) { qf[rt][0] = zz; qf[rt][1] = zz; }   // dead rows: S = 0
    }

    float nvv[4];
#pragma unroll
    for (int ds = 0; ds < 4; ds++) nvv[ds] = nv[ds * 16 + l15];

    f32x4 acc[2][4];   // row = rt*16 + quad*4 + reg, col d = ds*16 + l15
    f32x4 accl[2];     // row sums (denominator), same row layout
#pragma unroll
    for (int rt = 0; rt < 2; rt++)
#pragma unroll
        for (int reg = 0; reg < 4; reg++) {
            const float pr = __shfl(pnull[rt], quad * 4 + reg, 16);
            accl[rt][reg] = pr;
#pragma unroll
            for (int ds = 0; ds < 4; ds++)
                acc[rt][ds][reg] = pr * nvv[ds];
        }

    const f16* kg0 = kws + (size_t)bh * MM * DH;
    const f16* vg0 = vtws + (size_t)bh * DH * MM;
    const int sr = tid >> 1;          // 0..63
    const int sc = (tid & 1) * 32;    // 32-half (64 B) chunk
    const f16x4 vone = {(f16)1, (f16)1, (f16)1, (f16)1};

    for (int jc = 0; jc < MM; jc += 64) {
        uint4 kr[4], vr[4];
#pragma unroll
        for (int i = 0; i < 4; i++) {
            kr[i] = *(const uint4*)(kg0 + (size_t)(jc + sr) * DH + sc + i * 8);
            vr[i] = *(const uint4*)(vg0 + (size_t)sr * MM + jc + sc + i * 8);
        }
        int4 cmv[4];
#pragma unroll
        for (int jj = 0; jj < 4; jj++)
            cmv[jj] = *(const int4*)(cmask + (size_t)b * MM + jc + jj * 16 + quad * 4);

        __syncthreads();
#pragma unroll
        for (int i = 0; i < 4; i++) {
            *(uint4*)(sK + sr * 72 + sc + i * 8) = kr[i];
            *(uint4*)(sV + sr * 72 + sc + i * 8) = vr[i];
        }
        __syncthreads();

        // C-init: column mask (and dead-row override) folded into the MFMA
        f32x4 st[2][4];
#pragma unroll
        for (int rt = 0; rt < 2; rt++)
#pragma unroll
            for (int jj = 0; jj < 4; jj++) {
                st[rt][jj][0] = cmv[jj].x ? 0.0f : negsel[rt];
                st[rt][jj][1] = cmv[jj].y ? 0.0f : negsel[rt];
                st[rt][jj][2] = cmv[jj].z ? 0.0f : negsel[rt];
                st[rt][jj][3] = cmv[jj].w ? 0.0f : negsel[rt];
            }

        // S^T = K Q^T (C layout: j = quad*4+reg, r = l15)
#pragma unroll
        for (int ks = 0; ks < 2; ks++) {
            f16x8 kb[4];
#pragma unroll
            for (int jj = 0; jj < 4; jj++)
                kb[jj] = *(const f16x8*)(sK + (jj * 16 + l15) * 72 + ks * 32 + quad * 8);
#pragma unroll
            for (int rt = 0; rt < 2; rt++)
#pragma unroll
                for (int jj = 0; jj < 4; jj++)
                    st[rt][jj] = __builtin_amdgcn_mfma_f32_16x16x32_f16(
                        kb[jj], qf[rt][ks], st[rt][jj], 0, 0, 0);
        }

        // p = exp2(st)  (masked cols -> 0, dead rows -> 1); stays in registers
        f16x4 pa[2][4];
#pragma unroll
        for (int rt = 0; rt < 2; rt++)
#pragma unroll
            for (int jj = 0; jj < 4; jj++)
                pa[rt][jj] = pk4(EXP2(st[rt][jj][0]), EXP2(st[rt][jj][1]),
                                 EXP2(st[rt][jj][2]), EXP2(st[rt][jj][3]));

        // O += P V ; denominator += P . ones (MFMA, same layout as O)
#pragma unroll
        for (int jj = 0; jj < 4; jj++) {
            f16x4 vb[4];
#pragma unroll
            for (int ds = 0; ds < 4; ds++)
                vb[ds] = *(const f16x4*)(sV + (ds * 16 + l15) * 72 + jj * 16 + quad * 4);
#pragma unroll
            for (int rt = 0; rt < 2; rt++) {
#pragma unroll
                for (int ds = 0; ds < 4; ds++)
                    acc[rt][ds] = __builtin_amdgcn_mfma_f32_16x16x16f16(
                        pa[rt][jj], vb[ds], acc[rt][ds], 0, 0, 0);
                accl[rt] = __builtin_amdgcn_mfma_f32_16x16x16f16(
                    pa[rt][jj], vone, accl[rt], 0, 0, 0);
            }
        }
    }

    // epilogue: O / l -> bf16 hi/lo at [b*2048+n][h*64+d]
#pragma unroll
    for (int rt = 0; rt < 2; rt++) {
        float inv[4];
#pragma unroll
        for (int reg = 0; reg < 4; reg++) inv[reg] = 1.0f / accl[rt][reg];
#pragma unroll
        for (int ds = 0; ds < 4; ds++)
#pragma unroll
            for (int reg = 0; reg < 4; reg++) {
                const int r = q0 + rt * 16 + quad * 4 + reg;
                float v = acc[rt][ds][reg] * inv[reg];
                ushort hh, ll;
                bsplit(v, hh, ll);
                size_t idx = ((size_t)(b * 2048 + r)) * 512 + h * 64 + ds * 16 + l15;
                oh[idx] = hh;
                ol[idx] = ll;
            }
    }
}

// ---------------------------------------------------------------------------
// bf16x2-split MFMA GEMM for the final projection: out = O @ Wo + bias.
// ---------------------------------------------------------------------------
__launch_bounds__(256)
__global__ void mgemm2(const ushort* __restrict__ Ah, const ushort* __restrict__ Al,
                       const ushort* __restrict__ Bh, const ushort* __restrict__ Bl,
                       float* __restrict__ o32, const float* __restrict__ bias,
                       int K)
{
    __shared__ ushort sAh[128 * 36], sAl[128 * 36];
    __shared__ ushort sBh[64 * 36],  sBl[64 * 36];

    const int tid  = threadIdx.x;
    const int wave = tid >> 6, lane = tid & 63;
    const int l15  = lane & 15, quad = lane >> 4;
    const size_t r0 = (size_t)blockIdx.x * 128;
    const int c0 = blockIdx.y * 64;

    const int sr = tid >> 2;
    const int sc = (tid & 3) * 8;

    f32x4 acc[2][4] = {};

    for (int k0 = 0; k0 < K; k0 += 32) {
        uint4 ah0 = *(const uint4*)(Ah + (r0 + sr) * K + k0 + sc);
        uint4 ah1 = *(const uint4*)(Ah + (r0 + 64 + sr) * K + k0 + sc);
        uint4 al0 = *(const uint4*)(Al + (r0 + sr) * K + k0 + sc);
        uint4 al1 = *(const uint4*)(Al + (r0 + 64 + sr) * K + k0 + sc);
        uint4 bh  = *(const uint4*)(Bh + (size_t)(c0 + sr) * K + k0 + sc);
        uint4 bl  = *(const uint4*)(Bl + (size_t)(c0 + sr) * K + k0 + sc);
        __syncthreads();
        *(uint4*)(sAh + sr * 36 + sc)        = ah0;
        *(uint4*)(sAh + (64 + sr) * 36 + sc) = ah1;
        *(uint4*)(sAl + sr * 36 + sc)        = al0;
        *(uint4*)(sAl + (64 + sr) * 36 + sc) = al1;
        *(uint4*)(sBh + sr * 36 + sc)        = bh;
        *(uint4*)(sBl + sr * 36 + sc)        = bl;
        __syncthreads();

        bf16x8v a_h[2], a_l[2], b_h[4], b_l[4];
#pragma unroll
        for (int rt = 0; rt < 2; rt++) {
            const int r = wave * 32 + rt * 16 + l15;
            a_h[rt] = *(const bf16x8v*)(sAh + r * 36 + quad * 8);
            a_l[rt] = *(const bf16x8v*)(sAl + r * 36 + quad * 8);
        }
#pragma unroll
        for (int ct = 0; ct < 4; ct++) {
            const int c = ct * 16 + l15;
            b_h[ct] = *(const bf16x8v*)(sBh + c * 36 + quad * 8);
            b_l[ct] = *(const bf16x8v*)(sBl + c * 36 + quad * 8);
        }
#pragma unroll
        for (int rt = 0; rt < 2; rt++)
#pragma unroll
            for (int ct = 0; ct < 4; ct++) {
                acc[rt][ct] = __builtin_amdgcn_mfma_f32_16x16x32_bf16(a_h[rt], b_h[ct], acc[rt][ct], 0, 0, 0);
                acc[rt][ct] = __builtin_amdgcn_mfma_f32_16x16x32_bf16(a_h[rt], b_l[ct], acc[rt][ct], 0, 0, 0);
                acc[rt][ct] = __builtin_amdgcn_mfma_f32_16x16x32_bf16(a_l[rt], b_h[ct], acc[rt][ct], 0, 0, 0);
            }
    }

#pragma unroll
    for (int rt = 0; rt < 2; rt++)
#pragma unroll
        for (int ct = 0; ct < 4; ct++) {
            const int col = c0 + ct * 16 + l15;
            const float bv = bias[col];
#pragma unroll
            for (int reg = 0; reg < 4; reg++) {
                const size_t row = r0 + wave * 32 + rt * 16 + quad * 4 + reg;
                o32[row * 512 + col] = acc[rt][ct][reg] + bv;
            }
        }
}

extern "C" void kernel_launch(void* const* d_in, const int* in_sizes, int n_in,
                              void* d_out, int out_size, void* d_ws, size_t ws_size,
                              hipStream_t stream)
{
    const float* x    = (const float*)d_in[0];
    const float* ctx  = (const float*)d_in[1];
    const int*   mask = (const int*)d_in[2];
    const int*   cmsk = (const int*)d_in[3];
    const float* Wq   = (const float*)d_in[4];
    const float* Wkv  = (const float*)d_in[5];
    const float* Wo   = (const float*)d_in[6];
    const float* bo   = (const float*)d_in[7];
    const float* nk   = (const float*)d_in[8];
    const float* nv   = (const float*)d_in[9];
    float* out = (float*)d_out;

    const size_t S = (size_t)BB * HEADS * NN * DH;  // 4,194,304 elems

    f16* qws = (f16*)d_ws;
    f16* kws = qws + S;
    f16* vt  = kws + S;
    ushort* oh = (ushort*)(vt + S);
    ushort* ol = oh + S;
    f16* wq16  = (f16*)(ol + S);
    f16* wkv16 = wq16 + 512 * 512;
    ushort* woh = (ushort*)(wkv16 + 512 * 1024);
    ushort* wol = woh + 512 * 512;

    wtrans_k<<<dim3(16, 8),  256, 0, stream>>>(Wq,  wq16,  512, 512);
    wtrans_k<<<dim3(16, 16), 256, 0, stream>>>(Wkv, wkv16, 512, 1024);
    wsplit_k<<<dim3(16, 8),  256, 0, stream>>>(Wo,  woh, wol, 512, 512);
    fgemm<0><<<dim3(64, 8),  256, 0, stream>>>(x,   wq16,  qws, nullptr, 512);
    fgemm<1><<<dim3(64, 16), 256, 0, stream>>>(ctx, wkv16, kws, vt,      512);
    attn_k<<<dim3(32, 32), 128, 0, stream>>>(qws, kws, vt, mask, cmsk, nk, nv, oh, ol);
    mgemm2<<<dim3(64, 8),  256, 0, stream>>>(oh, ol, woh, wol, out, bo, 512);
}

// Round 7
// 226.533 us; speedup vs baseline: 1.4571x; 1.4571x over previous
//
#include <hip/hip_runtime.h>
#include <math.h>

#define BB 4
#define NN 2048
#define MM 2048
#define HEADS 8
#define DH 64

typedef _Float16 f16;
typedef _Float16 f16x4 __attribute__((ext_vector_type(4)));
typedef _Float16 f16x8 __attribute__((ext_vector_type(8)));
typedef float f32x4 __attribute__((ext_vector_type(4)));
typedef short bf16x8v __attribute__((ext_vector_type(8)));
typedef unsigned short ushort;

#define LOG2E 1.44269504088896f
#define QSCALE (0.125f * LOG2E)

#if __has_builtin(__builtin_amdgcn_exp2f)
#define EXP2(x) __builtin_amdgcn_exp2f(x)
#else
#define EXP2(x) exp2f(x)
#endif

__device__ __forceinline__ void bsplit(float v, ushort& h, ushort& l) {
    unsigned bits = __float_as_uint(v);
    float res = v - __uint_as_float(bits & 0xffff0000u);
    h = (ushort)(bits >> 16);
    l = (ushort)(__float_as_uint(res) >> 16);
}

__device__ __forceinline__ f16x4 pk4(float a, float b, float c, float d) {
#if __has_builtin(__builtin_amdgcn_cvt_pkrtz)
    auto t0 = __builtin_amdgcn_cvt_pkrtz(a, b);
    auto t1 = __builtin_amdgcn_cvt_pkrtz(c, d);
    f16x4 r;
    r[0] = t0[0]; r[1] = t0[1]; r[2] = t1[0]; r[3] = t1[1];
    return r;
#else
    f16x4 r = {(f16)a, (f16)b, (f16)c, (f16)d};
    return r;
#endif
}

// ---------------------------------------------------------------------------
// W [K][N] fp32 -> [N][K] bf16 hi/lo (for Wo, final bf16x2 GEMM)
// ---------------------------------------------------------------------------
__global__ void wsplit_k(const float* __restrict__ W, ushort* __restrict__ Th,
                         ushort* __restrict__ Tl, int K, int N)
{
    __shared__ ushort Sh[64][36], Sl[64][36];
    const int tid = threadIdx.x;
    const int k0 = blockIdx.x * 32, n0 = blockIdx.y * 64;
    const int kr = tid >> 3, nc = (tid & 7) * 8;
    float4 v0 = *(const float4*)(W + (size_t)(k0 + kr) * N + n0 + nc);
    float4 v1 = *(const float4*)(W + (size_t)(k0 + kr) * N + n0 + nc + 4);
    float e[8] = {v0.x, v0.y, v0.z, v0.w, v1.x, v1.y, v1.z, v1.w};
#pragma unroll
    for (int j = 0; j < 8; j++) {
        ushort h, l;
        bsplit(e[j], h, l);
        Sh[nc + j][kr] = h;
        Sl[nc + j][kr] = l;
    }
    __syncthreads();
    const int n = tid >> 2, kc = (tid & 3) * 8;
    *(uint4*)(Th + (size_t)(n0 + n) * K + k0 + kc) = *(const uint4*)(&Sh[n][kc]);
    *(uint4*)(Tl + (size_t)(n0 + n) * K + k0 + kc) = *(const uint4*)(&Sl[n][kc]);
}

// ---------------------------------------------------------------------------
// W [K][N] fp32 -> [N][K] f16 (for Wq, Wkv single-f16 GEMMs)
// ---------------------------------------------------------------------------
__global__ void wtrans_k(const float* __restrict__ W, f16* __restrict__ T16,
                         int K, int N)
{
    __shared__ f16 Sh[64][36];
    const int tid = threadIdx.x;
    const int k0 = blockIdx.x * 32, n0 = blockIdx.y * 64;
    const int kr = tid >> 3, nc = (tid & 7) * 8;
    float4 v0 = *(const float4*)(W + (size_t)(k0 + kr) * N + n0 + nc);
    float4 v1 = *(const float4*)(W + (size_t)(k0 + kr) * N + n0 + nc + 4);
    float e[8] = {v0.x, v0.y, v0.z, v0.w, v1.x, v1.y, v1.z, v1.w};
#pragma unroll
    for (int j = 0; j < 8; j++) Sh[nc + j][kr] = (f16)e[j];
    __syncthreads();
    const int n = tid >> 2, kc = (tid & 3) * 8;
    *(uint4*)(T16 + (size_t)(n0 + n) * K + k0 + kc) = *(const uint4*)(&Sh[n][kc]);
}

// ---------------------------------------------------------------------------
// Single-f16 MFMA GEMM: C = A(fp32, cvt in staging) @ Bt^T(f16 [N][K]).
// Tile 128x64, 4 waves (wave 32r x 64c), BK=32, 1 MFMA per sub-tile.
// MODE 0: qws f16 = tanh(acc)*0.125*log2e  (pre-scaled for exp2 softmax)
// MODE 1: by<8: kws f16 = tanh(acc); by>=8: vt f16 [bh][d][m] = acc
// ---------------------------------------------------------------------------
template<int MODE>
__launch_bounds__(256)
__global__ void fgemm(const float* __restrict__ A, const f16* __restrict__ Bt,
                      f16* __restrict__ o16a, f16* __restrict__ o16b, int K)
{
    __shared__ f16 sA[128 * 36];
    __shared__ f16 sB[64 * 36];

    const int tid  = threadIdx.x;
    const int wave = tid >> 6, lane = tid & 63;
    const int l15  = lane & 15, quad = lane >> 4;
    const size_t r0 = (size_t)blockIdx.x * 128;
    const int c0 = blockIdx.y * 64;

    const int ar = tid >> 1;           // 0..127
    const int ac = (tid & 1) * 16;     // 0 / 16
    const int br = tid >> 2;           // 0..63
    const int bc = (tid & 3) * 8;

    f32x4 acc[2][4] = {};

    for (int k0 = 0; k0 < K; k0 += 32) {
        const float* ap = A + (r0 + ar) * K + k0 + ac;
        float4 a0 = *(const float4*)(ap + 0);
        float4 a1 = *(const float4*)(ap + 4);
        float4 a2 = *(const float4*)(ap + 8);
        float4 a3 = *(const float4*)(ap + 12);
        uint4  bv = *(const uint4*)(Bt + (size_t)(c0 + br) * K + k0 + bc);
        f16x8 pa0, pa1;
        pa0[0] = (f16)a0.x; pa0[1] = (f16)a0.y; pa0[2] = (f16)a0.z; pa0[3] = (f16)a0.w;
        pa0[4] = (f16)a1.x; pa0[5] = (f16)a1.y; pa0[6] = (f16)a1.z; pa0[7] = (f16)a1.w;
        pa1[0] = (f16)a2.x; pa1[1] = (f16)a2.y; pa1[2] = (f16)a2.z; pa1[3] = (f16)a2.w;
        pa1[4] = (f16)a3.x; pa1[5] = (f16)a3.y; pa1[6] = (f16)a3.z; pa1[7] = (f16)a3.w;
        __syncthreads();
        *(f16x8*)(sA + ar * 36 + ac)     = pa0;
        *(f16x8*)(sA + ar * 36 + ac + 8) = pa1;
        *(uint4*)(sB + br * 36 + bc)     = bv;
        __syncthreads();

        f16x8 a[2], b[4];
#pragma unroll
        for (int rt = 0; rt < 2; rt++)
            a[rt] = *(const f16x8*)(sA + (wave * 32 + rt * 16 + l15) * 36 + quad * 8);
#pragma unroll
        for (int ct = 0; ct < 4; ct++)
            b[ct] = *(const f16x8*)(sB + (ct * 16 + l15) * 36 + quad * 8);
#pragma unroll
        for (int rt = 0; rt < 2; rt++)
#pragma unroll
            for (int ct = 0; ct < 4; ct++)
                acc[rt][ct] = __builtin_amdgcn_mfma_f32_16x16x32_f16(
                    a[rt], b[ct], acc[rt][ct], 0, 0, 0);
    }

    const int b    = (int)(r0 >> 11);
    const int rloc = ((int)(r0 & 2047)) + wave * 32;

#pragma unroll
    for (int rt = 0; rt < 2; rt++)
#pragma unroll
        for (int ct = 0; ct < 4; ct++) {
            if (MODE == 0 || (MODE == 1 && blockIdx.y < 8)) {
                const int h = blockIdx.y & 7;
                const int d = ct * 16 + l15;
#pragma unroll
                for (int reg = 0; reg < 4; reg++) {
                    const int n = rloc + rt * 16 + quad * 4 + reg;
                    float v = tanhf(acc[rt][ct][reg]);
                    if (MODE == 0) v *= QSCALE;
                    o16a[(((size_t)b * 8 + h) * 2048 + n) * 64 + d] = (f16)v;
                }
            } else {
                const int h = blockIdx.y - 8;
                const int d = ct * 16 + l15;
                const int m0 = rloc + rt * 16 + quad * 4;
                f16x4 pk;
#pragma unroll
                for (int reg = 0; reg < 4; reg++) pk[reg] = (f16)acc[rt][ct][reg];
                *(f16x4*)(o16b + (((size_t)b * 8 + h) * 64 + d) * 2048 + m0) = pk;
            }
        }
}

// ---------------------------------------------------------------------------
// MFMA fp16 flash attention v4 = v3 softmax machinery at v2 register shape.
// 256 thr = 4 waves, wave owns 16 q rows (no spills: ~60 VGPRs live).
// p = exp2(S') with column mask folded into MFMA C-init {0,-1e30}; q
// pre-scaled by 0.125*log2e; dead rows: zeroed Q + C-init 0 -> p=1 over 2049.
// Denominator via ones-column MFMA. No P LDS round-trip, no shuffles in loop.
// ---------------------------------------------------------------------------
__launch_bounds__(256)
__global__ void attn_k(const f16* __restrict__ qws, const f16* __restrict__ kws,
                       const f16* __restrict__ vtws,
                       const int* __restrict__ mask, const int* __restrict__ cmask,
                       const float* __restrict__ nk, const float* __restrict__ nv,
                       ushort* __restrict__ oh, ushort* __restrict__ ol)
{
    __shared__ f16 sK[64 * 72];      // [j][d]
    __shared__ f16 sV[64 * 72];      // [d][j]

    const int tid  = threadIdx.x;
    const int wave = tid >> 6, lane = tid & 63;
    const int l15  = lane & 15, quad = lane >> 4;
    const int bh = blockIdx.x, b = bh >> 3, h = bh & 7;
    const int q0 = blockIdx.y * 64 + wave * 16;

    // Q fragments, row r = l15 (pre-scaled by 0.125*log2e in fgemm<0>)
    f16x8 qf[2];
    const f16* qbase = qws + ((size_t)bh * NN + q0) * DH;
#pragma unroll
    for (int ks = 0; ks < 2; ks++)
        qf[ks] = *(const f16x8*)(qbase + l15 * DH + ks * 32 + quad * 8);

    // null-key logit for row l15 (log2-scaled via qf)
    float pn = 0.f;
#pragma unroll
    for (int ks = 0; ks < 2; ks++)
#pragma unroll
        for (int t = 0; t < 8; t++)
            pn += (float)qf[ks][t] * tanhf(nk[ks * 32 + quad * 8 + t]);
    pn += __shfl_xor(pn, 16);
    pn += __shfl_xor(pn, 32);

    const int rowOk = mask[(size_t)b * NN + q0 + l15];
    const float pnull  = rowOk ? EXP2(pn) : 1.0f;
    const float negsel = rowOk ? -1.0e30f : 0.0f;
    if (!rowOk) {
        const f16x8 zz = {(f16)0, (f16)0, (f16)0, (f16)0, (f16)0, (f16)0, (f16)0, (f16)0};
        qf[0] = zz; qf[1] = zz;       // dead rows: S contribution = 0
    }

    f32x4 acc[4];      // row = quad*4+reg, col d = ds*16+l15
    f32x4 accl;        // row sums (denominator), same row layout
#pragma unroll
    for (int reg = 0; reg < 4; reg++) {
        const float pr = __shfl(pnull, quad * 4 + reg, 16);
        accl[reg] = pr;
#pragma unroll
        for (int ds = 0; ds < 4; ds++)
            acc[ds][reg] = pr * nv[ds * 16 + l15];
    }

    const f16* kg0 = kws + (size_t)bh * MM * DH;
    const f16* vg0 = vtws + (size_t)bh * DH * MM;
    const int sr = tid >> 2;          // 0..63
    const int sc = (tid & 3) * 16;    // 16-half chunk
    const f16x4 vone = {(f16)1, (f16)1, (f16)1, (f16)1};

    for (int jc = 0; jc < MM; jc += 64) {
        uint4 kr0 = *(const uint4*)(kg0 + (size_t)(jc + sr) * DH + sc);
        uint4 kr1 = *(const uint4*)(kg0 + (size_t)(jc + sr) * DH + sc + 8);
        uint4 vr0 = *(const uint4*)(vg0 + (size_t)sr * MM + jc + sc);
        uint4 vr1 = *(const uint4*)(vg0 + (size_t)sr * MM + jc + sc + 8);
        int4 cmv[4];
#pragma unroll
        for (int jj = 0; jj < 4; jj++)
            cmv[jj] = *(const int4*)(cmask + (size_t)b * MM + jc + jj * 16 + quad * 4);

        __syncthreads();
        *(uint4*)(sK + sr * 72 + sc)     = kr0;
        *(uint4*)(sK + sr * 72 + sc + 8) = kr1;
        *(uint4*)(sV + sr * 72 + sc)     = vr0;
        *(uint4*)(sV + sr * 72 + sc + 8) = vr1;
        __syncthreads();

        // C-init: column mask (and dead-row override) folded into the MFMA
        f32x4 st[4];
#pragma unroll
        for (int jj = 0; jj < 4; jj++) {
            st[jj][0] = cmv[jj].x ? 0.0f : negsel;
            st[jj][1] = cmv[jj].y ? 0.0f : negsel;
            st[jj][2] = cmv[jj].z ? 0.0f : negsel;
            st[jj][3] = cmv[jj].w ? 0.0f : negsel;
        }

        // S^T = K Q^T (C layout: j = quad*4+reg, r = l15)
#pragma unroll
        for (int ks = 0; ks < 2; ks++) {
#pragma unroll
            for (int jj = 0; jj < 4; jj++) {
                f16x8 kb = *(const f16x8*)(sK + (jj * 16 + l15) * 72 + ks * 32 + quad * 8);
                st[jj] = __builtin_amdgcn_mfma_f32_16x16x32_f16(kb, qf[ks], st[jj], 0, 0, 0);
            }
        }

        // p = exp2(st): masked cols -> 0, dead rows -> 1; stays in registers
        f16x4 pa[4];
#pragma unroll
        for (int jj = 0; jj < 4; jj++)
            pa[jj] = pk4(EXP2(st[jj][0]), EXP2(st[jj][1]),
                         EXP2(st[jj][2]), EXP2(st[jj][3]));

        // O += P V ; denominator += P . ones (MFMA, same layout as O)
#pragma unroll
        for (int jj = 0; jj < 4; jj++) {
#pragma unroll
            for (int ds = 0; ds < 4; ds++) {
                f16x4 vb = *(const f16x4*)(sV + (ds * 16 + l15) * 72 + jj * 16 + quad * 4);
                acc[ds] = __builtin_amdgcn_mfma_f32_16x16x16f16(pa[jj], vb, acc[ds], 0, 0, 0);
            }
            accl = __builtin_amdgcn_mfma_f32_16x16x16f16(pa[jj], vone, accl, 0, 0, 0);
        }
    }

    // epilogue: O / l -> bf16 hi/lo at [b*2048+n][h*64+d]
    float inv[4];
#pragma unroll
    for (int reg = 0; reg < 4; reg++) inv[reg] = 1.0f / accl[reg];
#pragma unroll
    for (int ds = 0; ds < 4; ds++)
#pragma unroll
        for (int reg = 0; reg < 4; reg++) {
            const int r = q0 + quad * 4 + reg;
            float v = acc[ds][reg] * inv[reg];
            ushort hh, ll;
            bsplit(v, hh, ll);
            size_t idx = ((size_t)(b * 2048 + r)) * 512 + h * 64 + ds * 16 + l15;
            oh[idx] = hh;
            ol[idx] = ll;
        }
}

// ---------------------------------------------------------------------------
// bf16x2-split MFMA GEMM for the final projection: out = O @ Wo + bias.
// ---------------------------------------------------------------------------
__launch_bounds__(256)
__global__ void mgemm2(const ushort* __restrict__ Ah, const ushort* __restrict__ Al,
                       const ushort* __restrict__ Bh, const ushort* __restrict__ Bl,
                       float* __restrict__ o32, const float* __restrict__ bias,
                       int K)
{
    __shared__ ushort sAh[128 * 36], sAl[128 * 36];
    __shared__ ushort sBh[64 * 36],  sBl[64 * 36];

    const int tid  = threadIdx.x;
    const int wave = tid >> 6, lane = tid & 63;
    const int l15  = lane & 15, quad = lane >> 4;
    const size_t r0 = (size_t)blockIdx.x * 128;
    const int c0 = blockIdx.y * 64;

    const int sr = tid >> 2;
    const int sc = (tid & 3) * 8;

    f32x4 acc[2][4] = {};

    for (int k0 = 0; k0 < K; k0 += 32) {
        uint4 ah0 = *(const uint4*)(Ah + (r0 + sr) * K + k0 + sc);
        uint4 ah1 = *(const uint4*)(Ah + (r0 + 64 + sr) * K + k0 + sc);
        uint4 al0 = *(const uint4*)(Al + (r0 + sr) * K + k0 + sc);
        uint4 al1 = *(const uint4*)(Al + (r0 + 64 + sr) * K + k0 + sc);
        uint4 bh  = *(const uint4*)(Bh + (size_t)(c0 + sr) * K + k0 + sc);
        uint4 bl  = *(const uint4*)(Bl + (size_t)(c0 + sr) * K + k0 + sc);
        __syncthreads();
        *(uint4*)(sAh + sr * 36 + sc)        = ah0;
        *(uint4*)(sAh + (64 + sr) * 36 + sc) = ah1;
        *(uint4*)(sAl + sr * 36 + sc)        = al0;
        *(uint4*)(sAl + (64 + sr) * 36 + sc) = al1;
        *(uint4*)(sBh + sr * 36 + sc)        = bh;
        *(uint4*)(sBl + sr * 36 + sc)        = bl;
        __syncthreads();

        bf16x8v a_h[2], a_l[2], b_h[4], b_l[4];
#pragma unroll
        for (int rt = 0; rt < 2; rt++) {
            const int r = wave * 32 + rt * 16 + l15;
            a_h[rt] = *(const bf16x8v*)(sAh + r * 36 + quad * 8);
            a_l[rt] = *(const bf16x8v*)(sAl + r * 36 + quad * 8);
        }
#pragma unroll
        for (int ct = 0; ct < 4; ct++) {
            const int c = ct * 16 + l15;
            b_h[ct] = *(const bf16x8v*)(sBh + c * 36 + quad * 8);
            b_l[ct] = *(const bf16x8v*)(sBl + c * 36 + quad * 8);
        }
#pragma unroll
        for (int rt = 0; rt < 2; rt++)
#pragma unroll
            for (int ct = 0; ct < 4; ct++) {
                acc[rt][ct] = __builtin_amdgcn_mfma_f32_16x16x32_bf16(a_h[rt], b_h[ct], acc[rt][ct], 0, 0, 0);
                acc[rt][ct] = __builtin_amdgcn_mfma_f32_16x16x32_bf16(a_h[rt], b_l[ct], acc[rt][ct], 0, 0, 0);
                acc[rt][ct] = __builtin_amdgcn_mfma_f32_16x16x32_bf16(a_l[rt], b_h[ct], acc[rt][ct], 0, 0, 0);
            }
    }

#pragma unroll
    for (int rt = 0; rt < 2; rt++)
#pragma unroll
        for (int ct = 0; ct < 4; ct++) {
            const int col = c0 + ct * 16 + l15;
            const float bv = bias[col];
#pragma unroll
            for (int reg = 0; reg < 4; reg++) {
                const size_t row = r0 + wave * 32 + rt * 16 + quad * 4 + reg;
                o32[row * 512 + col] = acc[rt][ct][reg] + bv;
            }
        }
}

extern "C" void kernel_launch(void* const* d_in, const int* in_sizes, int n_in,
                              void* d_out, int out_size, void* d_ws, size_t ws_size,
                              hipStream_t stream)
{
    const float* x    = (const float*)d_in[0];
    const float* ctx  = (const float*)d_in[1];
    const int*   mask = (const int*)d_in[2];
    const int*   cmsk = (const int*)d_in[3];
    const float* Wq   = (const float*)d_in[4];
    const float* Wkv  = (const float*)d_in[5];
    const float* Wo   = (const float*)d_in[6];
    const float* bo   = (const float*)d_in[7];
    const float* nk   = (const float*)d_in[8];
    const float* nv   = (const float*)d_in[9];
    float* out = (float*)d_out;

    const size_t S = (size_t)BB * HEADS * NN * DH;  // 4,194,304 elems

    f16* qws = (f16*)d_ws;
    f16* kws = qws + S;
    f16* vt  = kws + S;
    ushort* oh = (ushort*)(vt + S);
    ushort* ol = oh + S;
    f16* wq16  = (f16*)(ol + S);
    f16* wkv16 = wq16 + 512 * 512;
    ushort* woh = (ushort*)(wkv16 + 512 * 1024);
    ushort* wol = woh + 512 * 512;

    wtrans_k<<<dim3(16, 8),  256, 0, stream>>>(Wq,  wq16,  512, 512);
    wtrans_k<<<dim3(16, 16), 256, 0, stream>>>(Wkv, wkv16, 512, 1024);
    wsplit_k<<<dim3(16, 8),  256, 0, stream>>>(Wo,  woh, wol, 512, 512);
    fgemm<0><<<dim3(64, 8),  256, 0, stream>>>(x,   wq16,  qws, nullptr, 512);
    fgemm<1><<<dim3(64, 16), 256, 0, stream>>>(ctx, wkv16, kws, vt,      512);
    attn_k<<<dim3(32, 32), 256, 0, stream>>>(qws, kws, vt, mask, cmsk, nk, nv, oh, ol);
    mgemm2<<<dim3(64, 8),  256, 0, stream>>>(oh, ol, woh, wol, out, bo, 512);
}

// Round 8
// 222.804 us; speedup vs baseline: 1.4815x; 1.0167x over previous
//
#include <hip/hip_runtime.h>
#include <math.h>

#define BB 4
#define NN 2048
#define MM 2048
#define HEADS 8
#define DH 64

typedef _Float16 f16;
typedef _Float16 f16x4 __attribute__((ext_vector_type(4)));
typedef _Float16 f16x8 __attribute__((ext_vector_type(8)));
typedef float f32x4 __attribute__((ext_vector_type(4)));
typedef short bf16x8v __attribute__((ext_vector_type(8)));
typedef unsigned short ushort;

#define LOG2E 1.44269504088896f
#define QSCALE (0.125f * LOG2E)

#if __has_builtin(__builtin_amdgcn_exp2f)
#define EXP2(x) __builtin_amdgcn_exp2f(x)
#else
#define EXP2(x) exp2f(x)
#endif

__device__ __forceinline__ void bsplit(float v, ushort& h, ushort& l) {
    unsigned bits = __float_as_uint(v);
    float res = v - __uint_as_float(bits & 0xffff0000u);
    h = (ushort)(bits >> 16);
    l = (ushort)(__float_as_uint(res) >> 16);
}

__device__ __forceinline__ f16x4 pk4(float a, float b, float c, float d) {
#if __has_builtin(__builtin_amdgcn_cvt_pkrtz)
    auto t0 = __builtin_amdgcn_cvt_pkrtz(a, b);
    auto t1 = __builtin_amdgcn_cvt_pkrtz(c, d);
    f16x4 r;
    r[0] = t0[0]; r[1] = t0[1]; r[2] = t1[0]; r[3] = t1[1];
    return r;
#else
    f16x4 r = {(f16)a, (f16)b, (f16)c, (f16)d};
    return r;
#endif
}

// ---------------------------------------------------------------------------
// Fused weight prep (1 launch): Wq->[N][K]f16, Wkv->[N][K]f16, Wo->[N][K]
// bf16 hi/lo. 512 blocks: [0,128) Wq, [128,384) Wkv, [384,512) Wo.
// ---------------------------------------------------------------------------
__global__ void wprep_k(const float* __restrict__ Wq, const float* __restrict__ Wkv,
                        const float* __restrict__ Wo,
                        f16* __restrict__ wq16, f16* __restrict__ wkv16,
                        ushort* __restrict__ woh, ushort* __restrict__ wol)
{
    __shared__ ushort S0[64 * 36], S1[64 * 36];
    const int tid = threadIdx.x;
    const int bid = blockIdx.x;
    const int K = 512;
    const float* W; int N; f16* T16; ushort *Th, *Tl; int id;
    if (bid < 128)      { W = Wq;  N = 512;  T16 = wq16;  Th = 0; Tl = 0; id = bid; }
    else if (bid < 384) { W = Wkv; N = 1024; T16 = wkv16; Th = 0; Tl = 0; id = bid - 128; }
    else                { W = Wo;  N = 512;  T16 = 0; Th = woh; Tl = wol; id = bid - 384; }
    const int k0 = (id & 15) * 32, n0 = (id >> 4) * 64;
    const int kr = tid >> 3, nc = (tid & 7) * 8;
    float4 v0 = *(const float4*)(W + (size_t)(k0 + kr) * N + n0 + nc);
    float4 v1 = *(const float4*)(W + (size_t)(k0 + kr) * N + n0 + nc + 4);
    float e[8] = {v0.x, v0.y, v0.z, v0.w, v1.x, v1.y, v1.z, v1.w};
    const int n = tid >> 2, kc = (tid & 3) * 8;
    if (T16) {
        f16* Sf = (f16*)S0;
#pragma unroll
        for (int j = 0; j < 8; j++) Sf[(nc + j) * 36 + kr] = (f16)e[j];
        __syncthreads();
        *(uint4*)(T16 + (size_t)(n0 + n) * K + k0 + kc) = *(const uint4*)(Sf + n * 36 + kc);
    } else {
#pragma unroll
        for (int j = 0; j < 8; j++) {
            ushort h, l;
            bsplit(e[j], h, l);
            S0[(nc + j) * 36 + kr] = h;
            S1[(nc + j) * 36 + kr] = l;
        }
        __syncthreads();
        *(uint4*)(Th + (size_t)(n0 + n) * K + k0 + kc) = *(const uint4*)(S0 + n * 36 + kc);
        *(uint4*)(Tl + (size_t)(n0 + n) * K + k0 + kc) = *(const uint4*)(S1 + n * 36 + kc);
    }
}

// ---------------------------------------------------------------------------
// Fused projections (1 launch): grid (64, 24).
// by 0..7  : Q  = tanh(x@Wq)*QSCALE   -> qws f16 [bh][n][d]
// by 8..15 : K  = tanh(ctx@Wkv[:512]) -> kws f16 [bh][m][d]
// by 16..23: V  = ctx@Wkv[512:]       -> vt  f16 [bh][d][m]
// Tile 128x64, 4 waves, BK=32, fp32->f16 cvt fused into A staging.
// ---------------------------------------------------------------------------
__launch_bounds__(256)
__global__ void proj_k(const float* __restrict__ x, const float* __restrict__ ctx,
                       const f16* __restrict__ wq16, const f16* __restrict__ wkv16,
                       f16* __restrict__ qws, f16* __restrict__ kws, f16* __restrict__ vt)
{
    __shared__ f16 sA[128 * 36];
    __shared__ f16 sB[64 * 36];

    const int tid  = threadIdx.x;
    const int wave = tid >> 6, lane = tid & 63;
    const int l15  = lane & 15, quad = lane >> 4;
    const int by = blockIdx.y;
    const int isQ = (by < 8);
    const float* A = isQ ? x : ctx;
    const f16* Bt  = isQ ? wq16 : wkv16;
    const int c0 = (isQ ? by : by - 8) * 64;
    const size_t r0 = (size_t)blockIdx.x * 128;
    const int K = 512;

    const int ar = tid >> 1;           // 0..127
    const int ac = (tid & 1) * 16;     // 0 / 16
    const int br = tid >> 2;           // 0..63
    const int bc = (tid & 3) * 8;

    f32x4 acc[2][4] = {};

    for (int k0 = 0; k0 < K; k0 += 32) {
        const float* ap = A + (r0 + ar) * K + k0 + ac;
        float4 a0 = *(const float4*)(ap + 0);
        float4 a1 = *(const float4*)(ap + 4);
        float4 a2 = *(const float4*)(ap + 8);
        float4 a3 = *(const float4*)(ap + 12);
        uint4  bv = *(const uint4*)(Bt + (size_t)(c0 + br) * K + k0 + bc);
        f16x8 pa0, pa1;
        pa0[0] = (f16)a0.x; pa0[1] = (f16)a0.y; pa0[2] = (f16)a0.z; pa0[3] = (f16)a0.w;
        pa0[4] = (f16)a1.x; pa0[5] = (f16)a1.y; pa0[6] = (f16)a1.z; pa0[7] = (f16)a1.w;
        pa1[0] = (f16)a2.x; pa1[1] = (f16)a2.y; pa1[2] = (f16)a2.z; pa1[3] = (f16)a2.w;
        pa1[4] = (f16)a3.x; pa1[5] = (f16)a3.y; pa1[6] = (f16)a3.z; pa1[7] = (f16)a3.w;
        __syncthreads();
        *(f16x8*)(sA + ar * 36 + ac)     = pa0;
        *(f16x8*)(sA + ar * 36 + ac + 8) = pa1;
        *(uint4*)(sB + br * 36 + bc)     = bv;
        __syncthreads();

        f16x8 a[2], b[4];
#pragma unroll
        for (int rt = 0; rt < 2; rt++)
            a[rt] = *(const f16x8*)(sA + (wave * 32 + rt * 16 + l15) * 36 + quad * 8);
#pragma unroll
        for (int ct = 0; ct < 4; ct++)
            b[ct] = *(const f16x8*)(sB + (ct * 16 + l15) * 36 + quad * 8);
#pragma unroll
        for (int rt = 0; rt < 2; rt++)
#pragma unroll
            for (int ct = 0; ct < 4; ct++)
                acc[rt][ct] = __builtin_amdgcn_mfma_f32_16x16x32_f16(
                    a[rt], b[ct], acc[rt][ct], 0, 0, 0);
    }

    const int b    = (int)(r0 >> 11);
    const int rloc = ((int)(r0 & 2047)) + wave * 32;

#pragma unroll
    for (int rt = 0; rt < 2; rt++)
#pragma unroll
        for (int ct = 0; ct < 4; ct++) {
            if (by < 16) {               // Q or K (tanh path)
                const int h = by & 7;
                const int d = ct * 16 + l15;
                f16* dst = isQ ? qws : kws;
                const float sc = isQ ? QSCALE : 1.0f;
#pragma unroll
                for (int reg = 0; reg < 4; reg++) {
                    const int nn = rloc + rt * 16 + quad * 4 + reg;
                    dst[(((size_t)b * 8 + h) * 2048 + nn) * 64 + d] =
                        (f16)(tanhf(acc[rt][ct][reg]) * sc);
                }
            } else {                      // V, transposed
                const int h = by - 16;
                const int d = ct * 16 + l15;
                const int m0 = rloc + rt * 16 + quad * 4;
                f16x4 pk;
#pragma unroll
                for (int reg = 0; reg < 4; reg++) pk[reg] = (f16)acc[rt][ct][reg];
                *(f16x4*)(vt + (((size_t)b * 8 + h) * 64 + d) * 2048 + m0) = pk;
            }
        }
}

// ---------------------------------------------------------------------------
// MFMA fp16 flash attention v5: v4 machinery + j-split for occupancy.
// Grid (32 bh, 32 q-blocks, 2 j-halves) = 2048 blocks -> 8 blocks/CU.
// Fixed-shift softmax p = exp2(S') makes the split-merge EXACT:
// O = (O1 + O2) / (l1 + l2). Null token lives in jh==0 only.
// Partials: Op f32 [jh][b*2048+n][h*64+d], lp f32 [jh][bh][n].
// ---------------------------------------------------------------------------
__launch_bounds__(256)
__global__ void attn_k(const f16* __restrict__ qws, const f16* __restrict__ kws,
                       const f16* __restrict__ vtws,
                       const int* __restrict__ mask, const int* __restrict__ cmask,
                       const float* __restrict__ nk, const float* __restrict__ nv,
                       float* __restrict__ Op, float* __restrict__ lp)
{
    __shared__ f16 sK[64 * 72];      // [j][d]
    __shared__ f16 sV[64 * 72];      // [d][j]

    const int tid  = threadIdx.x;
    const int wave = tid >> 6, lane = tid & 63;
    const int l15  = lane & 15, quad = lane >> 4;
    const int bh = blockIdx.x, b = bh >> 3, h = bh & 7;
    const int q0 = blockIdx.y * 64 + wave * 16;
    const int jh = blockIdx.z;

    // Q fragments, row r = l15 (pre-scaled by 0.125*log2e in proj_k)
    f16x8 qf[2];
    const f16* qbase = qws + ((size_t)bh * NN + q0) * DH;
#pragma unroll
    for (int ks = 0; ks < 2; ks++)
        qf[ks] = *(const f16x8*)(qbase + l15 * DH + ks * 32 + quad * 8);

    const int rowOk = mask[(size_t)b * NN + q0 + l15];
    const float negsel = rowOk ? -1.0e30f : 0.0f;

    // null-token init only in the jh==0 half
    float pnull = 0.0f;
    if (jh == 0) {
        float pn = 0.f;
#pragma unroll
        for (int ks = 0; ks < 2; ks++)
#pragma unroll
            for (int t = 0; t < 8; t++)
                pn += (float)qf[ks][t] * tanhf(nk[ks * 32 + quad * 8 + t]);
        pn += __shfl_xor(pn, 16);
        pn += __shfl_xor(pn, 32);
        pnull = rowOk ? EXP2(pn) : 1.0f;
    }
    if (!rowOk) {
        const f16x8 zz = {(f16)0, (f16)0, (f16)0, (f16)0, (f16)0, (f16)0, (f16)0, (f16)0};
        qf[0] = zz; qf[1] = zz;       // dead rows: S contribution = 0
    }

    f32x4 acc[4];      // row = quad*4+reg, col d = ds*16+l15
    f32x4 accl;        // row sums, same row layout
#pragma unroll
    for (int reg = 0; reg < 4; reg++) {
        const float pr = __shfl(pnull, quad * 4 + reg, 16);
        accl[reg] = pr;
#pragma unroll
        for (int ds = 0; ds < 4; ds++)
            acc[ds][reg] = pr * nv[ds * 16 + l15];
    }

    const f16* kg0 = kws + (size_t)bh * MM * DH;
    const f16* vg0 = vtws + (size_t)bh * DH * MM;
    const int sr = tid >> 2;          // 0..63
    const int sc = (tid & 3) * 16;    // 16-half chunk
    const f16x4 vone = {(f16)1, (f16)1, (f16)1, (f16)1};
    const int jbeg = jh << 10, jend = jbeg + 1024;

    for (int jc = jbeg; jc < jend; jc += 64) {
        uint4 kr0 = *(const uint4*)(kg0 + (size_t)(jc + sr) * DH + sc);
        uint4 kr1 = *(const uint4*)(kg0 + (size_t)(jc + sr) * DH + sc + 8);
        uint4 vr0 = *(const uint4*)(vg0 + (size_t)sr * MM + jc + sc);
        uint4 vr1 = *(const uint4*)(vg0 + (size_t)sr * MM + jc + sc + 8);
        int4 cmv[4];
#pragma unroll
        for (int jj = 0; jj < 4; jj++)
            cmv[jj] = *(const int4*)(cmask + (size_t)b * MM + jc + jj * 16 + quad * 4);

        __syncthreads();
        *(uint4*)(sK + sr * 72 + sc)     = kr0;
        *(uint4*)(sK + sr * 72 + sc + 8) = kr1;
        *(uint4*)(sV + sr * 72 + sc)     = vr0;
        *(uint4*)(sV + sr * 72 + sc + 8) = vr1;
        __syncthreads();

        // C-init: column mask (and dead-row override) folded into the MFMA
        f32x4 st[4];
#pragma unroll
        for (int jj = 0; jj < 4; jj++) {
            st[jj][0] = cmv[jj].x ? 0.0f : negsel;
            st[jj][1] = cmv[jj].y ? 0.0f : negsel;
            st[jj][2] = cmv[jj].z ? 0.0f : negsel;
            st[jj][3] = cmv[jj].w ? 0.0f : negsel;
        }

        // S^T = K Q^T (C layout: j = quad*4+reg, r = l15)
#pragma unroll
        for (int ks = 0; ks < 2; ks++) {
#pragma unroll
            for (int jj = 0; jj < 4; jj++) {
                f16x8 kb = *(const f16x8*)(sK + (jj * 16 + l15) * 72 + ks * 32 + quad * 8);
                st[jj] = __builtin_amdgcn_mfma_f32_16x16x32_f16(kb, qf[ks], st[jj], 0, 0, 0);
            }
        }

        // p = exp2(st): masked cols -> 0, dead rows -> 1; stays in registers
        f16x4 pa[4];
#pragma unroll
        for (int jj = 0; jj < 4; jj++)
            pa[jj] = pk4(EXP2(st[jj][0]), EXP2(st[jj][1]),
                         EXP2(st[jj][2]), EXP2(st[jj][3]));

        // O += P V ; denominator += P . ones (MFMA, same layout as O)
#pragma unroll
        for (int jj = 0; jj < 4; jj++) {
#pragma unroll
            for (int ds = 0; ds < 4; ds++) {
                f16x4 vb = *(const f16x4*)(sV + (ds * 16 + l15) * 72 + jj * 16 + quad * 4);
                acc[ds] = __builtin_amdgcn_mfma_f32_16x16x16f16(pa[jj], vb, acc[ds], 0, 0, 0);
            }
            accl = __builtin_amdgcn_mfma_f32_16x16x16f16(pa[jj], vone, accl, 0, 0, 0);
        }
    }

    // epilogue: raw partials (merge divides)
#pragma unroll
    for (int ds = 0; ds < 4; ds++)
#pragma unroll
        for (int reg = 0; reg < 4; reg++) {
            const int r = q0 + quad * 4 + reg;
            Op[((size_t)jh * 8192 + b * 2048 + r) * 512 + h * 64 + ds * 16 + l15] =
                acc[ds][reg];
        }
    if (l15 == 0) {
#pragma unroll
        for (int reg = 0; reg < 4; reg++)
            lp[((size_t)jh * 32 + bh) * 2048 + q0 + quad * 4 + reg] = accl[reg];
    }
}

// ---------------------------------------------------------------------------
// Merge j-halves: O = (O1+O2)/(l1+l2), bsplit -> oh/ol (bf16x2 A for mgemm2).
// ---------------------------------------------------------------------------
__global__ void merge_k(const float* __restrict__ Op, const float* __restrict__ lp,
                        ushort* __restrict__ oh, ushort* __restrict__ ol)
{
    const int i = blockIdx.x * 256 + threadIdx.x;   // 1,048,576 threads
    const int row = i >> 7;                          // 0..8191
    const int c4  = i & 127;
    const int b = row >> 11, n = row & 2047, h = c4 >> 4;
    const float l = lp[((size_t)b * 8 + h) * 2048 + n] +
                    lp[((size_t)32 + b * 8 + h) * 2048 + n];
    const float inv = 1.0f / l;
    const float4 o1 = *(const float4*)(Op + (size_t)row * 512 + c4 * 4);
    const float4 o2 = *(const float4*)(Op + (size_t)(8192 + row) * 512 + c4 * 4);
    float v[4] = {(o1.x + o2.x) * inv, (o1.y + o2.y) * inv,
                  (o1.z + o2.z) * inv, (o1.w + o2.w) * inv};
    ushort hh[4], ll[4];
#pragma unroll
    for (int j = 0; j < 4; j++) bsplit(v[j], hh[j], ll[j]);
    ushort4 H = {hh[0], hh[1], hh[2], hh[3]};
    ushort4 L = {ll[0], ll[1], ll[2], ll[3]};
    *(ushort4*)(oh + (size_t)row * 512 + c4 * 4) = H;
    *(ushort4*)(ol + (size_t)row * 512 + c4 * 4) = L;
}

// ---------------------------------------------------------------------------
// bf16x2-split MFMA GEMM for the final projection: out = O @ Wo + bias.
// ---------------------------------------------------------------------------
__launch_bounds__(256)
__global__ void mgemm2(const ushort* __restrict__ Ah, const ushort* __restrict__ Al,
                       const ushort* __restrict__ Bh, const ushort* __restrict__ Bl,
                       float* __restrict__ o32, const float* __restrict__ bias,
                       int K)
{
    __shared__ ushort sAh[128 * 36], sAl[128 * 36];
    __shared__ ushort sBh[64 * 36],  sBl[64 * 36];

    const int tid  = threadIdx.x;
    const int wave = tid >> 6, lane = tid & 63;
    const int l15  = lane & 15, quad = lane >> 4;
    const size_t r0 = (size_t)blockIdx.x * 128;
    const int c0 = blockIdx.y * 64;

    const int sr = tid >> 2;
    const int sc = (tid & 3) * 8;

    f32x4 acc[2][4] = {};

    for (int k0 = 0; k0 < K; k0 += 32) {
        uint4 ah0 = *(const uint4*)(Ah + (r0 + sr) * K + k0 + sc);
        uint4 ah1 = *(const uint4*)(Ah + (r0 + 64 + sr) * K + k0 + sc);
        uint4 al0 = *(const uint4*)(Al + (r0 + sr) * K + k0 + sc);
        uint4 al1 = *(const uint4*)(Al + (r0 + 64 + sr) * K + k0 + sc);
        uint4 bh  = *(const uint4*)(Bh + (size_t)(c0 + sr) * K + k0 + sc);
        uint4 bl  = *(const uint4*)(Bl + (size_t)(c0 + sr) * K + k0 + sc);
        __syncthreads();
        *(uint4*)(sAh + sr * 36 + sc)        = ah0;
        *(uint4*)(sAh + (64 + sr) * 36 + sc) = ah1;
        *(uint4*)(sAl + sr * 36 + sc)        = al0;
        *(uint4*)(sAl + (64 + sr) * 36 + sc) = al1;
        *(uint4*)(sBh + sr * 36 + sc)        = bh;
        *(uint4*)(sBl + sr * 36 + sc)        = bl;
        __syncthreads();

        bf16x8v a_h[2], a_l[2], b_h[4], b_l[4];
#pragma unroll
        for (int rt = 0; rt < 2; rt++) {
            const int r = wave * 32 + rt * 16 + l15;
            a_h[rt] = *(const bf16x8v*)(sAh + r * 36 + quad * 8);
            a_l[rt] = *(const bf16x8v*)(sAl + r * 36 + quad * 8);
        }
#pragma unroll
        for (int ct = 0; ct < 4; ct++) {
            const int c = ct * 16 + l15;
            b_h[ct] = *(const bf16x8v*)(sBh + c * 36 + quad * 8);
            b_l[ct] = *(const bf16x8v*)(sBl + c * 36 + quad * 8);
        }
#pragma unroll
        for (int rt = 0; rt < 2; rt++)
#pragma unroll
            for (int ct = 0; ct < 4; ct++) {
                acc[rt][ct] = __builtin_amdgcn_mfma_f32_16x16x32_bf16(a_h[rt], b_h[ct], acc[rt][ct], 0, 0, 0);
                acc[rt][ct] = __builtin_amdgcn_mfma_f32_16x16x32_bf16(a_h[rt], b_l[ct], acc[rt][ct], 0, 0, 0);
                acc[rt][ct] = __builtin_amdgcn_mfma_f32_16x16x32_bf16(a_l[rt], b_h[ct], acc[rt][ct], 0, 0, 0);
            }
    }

#pragma unroll
    for (int rt = 0; rt < 2; rt++)
#pragma unroll
        for (int ct = 0; ct < 4; ct++) {
            const int col = c0 + ct * 16 + l15;
            const float bv = bias[col];
#pragma unroll
            for (int reg = 0; reg < 4; reg++) {
                const size_t row = r0 + wave * 32 + rt * 16 + quad * 4 + reg;
                o32[row * 512 + col] = acc[rt][ct][reg] + bv;
            }
        }
}

extern "C" void kernel_launch(void* const* d_in, const int* in_sizes, int n_in,
                              void* d_out, int out_size, void* d_ws, size_t ws_size,
                              hipStream_t stream)
{
    const float* x    = (const float*)d_in[0];
    const float* ctx  = (const float*)d_in[1];
    const int*   mask = (const int*)d_in[2];
    const int*   cmsk = (const int*)d_in[3];
    const float* Wq   = (const float*)d_in[4];
    const float* Wkv  = (const float*)d_in[5];
    const float* Wo   = (const float*)d_in[6];
    const float* bo   = (const float*)d_in[7];
    const float* nk   = (const float*)d_in[8];
    const float* nv   = (const float*)d_in[9];
    float* out = (float*)d_out;

    const size_t S = (size_t)BB * HEADS * NN * DH;  // 4,194,304 elems

    f16* qws = (f16*)d_ws;                  // 8 MB
    f16* kws = qws + S;                     // 8 MB
    f16* vt  = kws + S;                     // 8 MB
    f16* wq16  = vt + S;                    // 0.5 MB
    f16* wkv16 = wq16 + 512 * 512;          // 1 MB
    ushort* woh = (ushort*)(wkv16 + 512 * 1024);   // 0.5 MB
    ushort* wol = woh + 512 * 512;                 // 0.5 MB
    float* lp = (float*)(wol + 512 * 512);         // 2*32*2048 f32 = 0.5 MB
    float* Op = lp + 2 * 32 * 2048;                // 2*8192*512 f32 = 32 MB
    // oh/ol alias qws/kws (dead after attn_k; merge_k writes them afterwards)
    ushort* oh = (ushort*)qws;
    ushort* ol = (ushort*)kws;

    wprep_k<<<512, 256, 0, stream>>>(Wq, Wkv, Wo, wq16, wkv16, woh, wol);
    proj_k<<<dim3(64, 24), 256, 0, stream>>>(x, ctx, wq16, wkv16, qws, kws, vt);
    attn_k<<<dim3(32, 32, 2), 256, 0, stream>>>(qws, kws, vt, mask, cmsk, nk, nv, Op, lp);
    merge_k<<<4096, 256, 0, stream>>>(Op, lp, oh, ol);
    mgemm2<<<dim3(64, 8), 256, 0, stream>>>(oh, ol, woh, wol, out, bo, 512);
}

// Round 9
// 204.972 us; speedup vs baseline: 1.6104x; 1.0870x over previous
//
#include <hip/hip_runtime.h>
#include <math.h>

#define BB 4
#define NN 2048
#define MM 2048
#define HEADS 8
#define DH 64

typedef _Float16 f16;
typedef _Float16 f16x4 __attribute__((ext_vector_type(4)));
typedef _Float16 f16x8 __attribute__((ext_vector_type(8)));
typedef float f32x4 __attribute__((ext_vector_type(4)));
typedef short bf16x8v __attribute__((ext_vector_type(8)));
typedef unsigned short ushort;

#define LOG2E 1.44269504088896f
#define QSCALE (0.125f * LOG2E)

#if __has_builtin(__builtin_amdgcn_exp2f)
#define EXP2(x) __builtin_amdgcn_exp2f(x)
#else
#define EXP2(x) exp2f(x)
#endif

__device__ __forceinline__ void bsplit(float v, ushort& h, ushort& l) {
    unsigned bits = __float_as_uint(v);
    float res = v - __uint_as_float(bits & 0xffff0000u);
    h = (ushort)(bits >> 16);
    l = (ushort)(__float_as_uint(res) >> 16);
}

__device__ __forceinline__ f16x4 pk4(float a, float b, float c, float d) {
#if __has_builtin(__builtin_amdgcn_cvt_pkrtz)
    auto t0 = __builtin_amdgcn_cvt_pkrtz(a, b);
    auto t1 = __builtin_amdgcn_cvt_pkrtz(c, d);
    f16x4 r;
    r[0] = t0[0]; r[1] = t0[1]; r[2] = t1[0]; r[3] = t1[1];
    return r;
#else
    f16x4 r = {(f16)a, (f16)b, (f16)c, (f16)d};
    return r;
#endif
}

// ---------------------------------------------------------------------------
// Fused weight prep (1 launch): Wq->[N][K]f16, Wkv->[N][K]f16, Wo->[N][K]
// bf16 hi/lo. 512 blocks: [0,128) Wq, [128,384) Wkv, [384,512) Wo.
// ---------------------------------------------------------------------------
__global__ void wprep_k(const float* __restrict__ Wq, const float* __restrict__ Wkv,
                        const float* __restrict__ Wo,
                        f16* __restrict__ wq16, f16* __restrict__ wkv16,
                        ushort* __restrict__ woh, ushort* __restrict__ wol)
{
    __shared__ ushort S0[64 * 36], S1[64 * 36];
    const int tid = threadIdx.x;
    const int bid = blockIdx.x;
    const int K = 512;
    const float* W; int N; f16* T16; ushort *Th, *Tl; int id;
    if (bid < 128)      { W = Wq;  N = 512;  T16 = wq16;  Th = 0; Tl = 0; id = bid; }
    else if (bid < 384) { W = Wkv; N = 1024; T16 = wkv16; Th = 0; Tl = 0; id = bid - 128; }
    else                { W = Wo;  N = 512;  T16 = 0; Th = woh; Tl = wol; id = bid - 384; }
    const int k0 = (id & 15) * 32, n0 = (id >> 4) * 64;
    const int kr = tid >> 3, nc = (tid & 7) * 8;
    float4 v0 = *(const float4*)(W + (size_t)(k0 + kr) * N + n0 + nc);
    float4 v1 = *(const float4*)(W + (size_t)(k0 + kr) * N + n0 + nc + 4);
    float e[8] = {v0.x, v0.y, v0.z, v0.w, v1.x, v1.y, v1.z, v1.w};
    const int n = tid >> 2, kc = (tid & 3) * 8;
    if (T16) {
        f16* Sf = (f16*)S0;
#pragma unroll
        for (int j = 0; j < 8; j++) Sf[(nc + j) * 36 + kr] = (f16)e[j];
        __syncthreads();
        *(uint4*)(T16 + (size_t)(n0 + n) * K + k0 + kc) = *(const uint4*)(Sf + n * 36 + kc);
    } else {
#pragma unroll
        for (int j = 0; j < 8; j++) {
            ushort h, l;
            bsplit(e[j], h, l);
            S0[(nc + j) * 36 + kr] = h;
            S1[(nc + j) * 36 + kr] = l;
        }
        __syncthreads();
        *(uint4*)(Th + (size_t)(n0 + n) * K + k0 + kc) = *(const uint4*)(S0 + n * 36 + kc);
        *(uint4*)(Tl + (size_t)(n0 + n) * K + k0 + kc) = *(const uint4*)(S1 + n * 36 + kc);
    }
}

// ---------------------------------------------------------------------------
// Fused projections (1 launch): grid (64, 24).
// by 0..7  : Q  = tanh(x@Wq)*QSCALE   -> qws f16 [bh][n][d]
// by 8..15 : K  = tanh(ctx@Wkv[:512]) -> kws f16 [bh][m][d]
// by 16..23: V  = ctx@Wkv[512:]       -> vt  f16 [bh][d][m]
// ---------------------------------------------------------------------------
__launch_bounds__(256)
__global__ void proj_k(const float* __restrict__ x, const float* __restrict__ ctx,
                       const f16* __restrict__ wq16, const f16* __restrict__ wkv16,
                       f16* __restrict__ qws, f16* __restrict__ kws, f16* __restrict__ vt)
{
    __shared__ f16 sA[128 * 36];
    __shared__ f16 sB[64 * 36];

    const int tid  = threadIdx.x;
    const int wave = tid >> 6, lane = tid & 63;
    const int l15  = lane & 15, quad = lane >> 4;
    const int by = blockIdx.y;
    const int isQ = (by < 8);
    const float* A = isQ ? x : ctx;
    const f16* Bt  = isQ ? wq16 : wkv16;
    const int c0 = (isQ ? by : by - 8) * 64;
    const size_t r0 = (size_t)blockIdx.x * 128;
    const int K = 512;

    const int ar = tid >> 1;           // 0..127
    const int ac = (tid & 1) * 16;     // 0 / 16
    const int br = tid >> 2;           // 0..63
    const int bc = (tid & 3) * 8;

    f32x4 acc[2][4] = {};

    for (int k0 = 0; k0 < K; k0 += 32) {
        const float* ap = A + (r0 + ar) * K + k0 + ac;
        float4 a0 = *(const float4*)(ap + 0);
        float4 a1 = *(const float4*)(ap + 4);
        float4 a2 = *(const float4*)(ap + 8);
        float4 a3 = *(const float4*)(ap + 12);
        uint4  bv = *(const uint4*)(Bt + (size_t)(c0 + br) * K + k0 + bc);
        f16x8 pa0, pa1;
        pa0[0] = (f16)a0.x; pa0[1] = (f16)a0.y; pa0[2] = (f16)a0.z; pa0[3] = (f16)a0.w;
        pa0[4] = (f16)a1.x; pa0[5] = (f16)a1.y; pa0[6] = (f16)a1.z; pa0[7] = (f16)a1.w;
        pa1[0] = (f16)a2.x; pa1[1] = (f16)a2.y; pa1[2] = (f16)a2.z; pa1[3] = (f16)a2.w;
        pa1[4] = (f16)a3.x; pa1[5] = (f16)a3.y; pa1[6] = (f16)a3.z; pa1[7] = (f16)a3.w;
        __syncthreads();
        *(f16x8*)(sA + ar * 36 + ac)     = pa0;
        *(f16x8*)(sA + ar * 36 + ac + 8) = pa1;
        *(uint4*)(sB + br * 36 + bc)     = bv;
        __syncthreads();

        f16x8 a[2], b[4];
#pragma unroll
        for (int rt = 0; rt < 2; rt++)
            a[rt] = *(const f16x8*)(sA + (wave * 32 + rt * 16 + l15) * 36 + quad * 8);
#pragma unroll
        for (int ct = 0; ct < 4; ct++)
            b[ct] = *(const f16x8*)(sB + (ct * 16 + l15) * 36 + quad * 8);
#pragma unroll
        for (int rt = 0; rt < 2; rt++)
#pragma unroll
            for (int ct = 0; ct < 4; ct++)
                acc[rt][ct] = __builtin_amdgcn_mfma_f32_16x16x32_f16(
                    a[rt], b[ct], acc[rt][ct], 0, 0, 0);
    }

    const int b    = (int)(r0 >> 11);
    const int rloc = ((int)(r0 & 2047)) + wave * 32;

#pragma unroll
    for (int rt = 0; rt < 2; rt++)
#pragma unroll
        for (int ct = 0; ct < 4; ct++) {
            if (by < 16) {               // Q or K (tanh path)
                const int h = by & 7;
                const int d = ct * 16 + l15;
                f16* dst = isQ ? qws : kws;
                const float sc = isQ ? QSCALE : 1.0f;
#pragma unroll
                for (int reg = 0; reg < 4; reg++) {
                    const int nn = rloc + rt * 16 + quad * 4 + reg;
                    dst[(((size_t)b * 8 + h) * 2048 + nn) * 64 + d] =
                        (f16)(tanhf(acc[rt][ct][reg]) * sc);
                }
            } else {                      // V, transposed
                const int h = by - 16;
                const int d = ct * 16 + l15;
                const int m0 = rloc + rt * 16 + quad * 4;
                f16x4 pk;
#pragma unroll
                for (int reg = 0; reg < 4; reg++) pk[reg] = (f16)acc[rt][ct][reg];
                *(f16x4*)(vt + (((size_t)b * 8 + h) * 64 + d) * 2048 + m0) = pk;
            }
        }
}

// ---------------------------------------------------------------------------
// MFMA fp16 flash attention v6: 32 q-rows per wave (halves per-CU LDS reads:
// each K/V LDS fragment feeds 2 MFMAs). 128 rows/block, grid (32,16,2).
// __launch_bounds__(256,4) -> 128 VGPR budget (round-6 spill fix).
// Fixed-shift softmax p = exp2(S'), mask in MFMA C-init, denominator via
// ones-column MFMA. Split-merge exact: O = (O1+O2)/(l1+l2).
// ---------------------------------------------------------------------------
__launch_bounds__(256, 4)
__global__ void attn_k(const f16* __restrict__ qws, const f16* __restrict__ kws,
                       const f16* __restrict__ vtws,
                       const int* __restrict__ mask, const int* __restrict__ cmask,
                       const float* __restrict__ nk, const float* __restrict__ nv,
                       float* __restrict__ Op, float* __restrict__ lp)
{
    __shared__ f16 sK[64 * 72];      // [j][d]
    __shared__ f16 sV[64 * 72];      // [d][j]

    const int tid  = threadIdx.x;
    const int wave = tid >> 6, lane = tid & 63;
    const int l15  = lane & 15, quad = lane >> 4;
    const int bh = blockIdx.x, b = bh >> 3, h = bh & 7;
    const int q0 = blockIdx.y * 128 + wave * 32;
    const int jh = blockIdx.z;

    // Q fragments, rows rt*16 + l15 (pre-scaled by 0.125*log2e in proj_k)
    f16x8 qf[2][2];
    const f16* qbase = qws + ((size_t)bh * NN + q0) * DH;
#pragma unroll
    for (int rt = 0; rt < 2; rt++)
#pragma unroll
        for (int ks = 0; ks < 2; ks++)
            qf[rt][ks] = *(const f16x8*)(qbase + (rt * 16 + l15) * DH + ks * 32 + quad * 8);

    int rowOk[2];
#pragma unroll
    for (int rt = 0; rt < 2; rt++)
        rowOk[rt] = mask[(size_t)b * NN + q0 + rt * 16 + l15];

    // null-token init only in the jh==0 half
    float pnull[2] = {0.0f, 0.0f};
    if (jh == 0) {
        float pn[2] = {0.f, 0.f};
#pragma unroll
        for (int ks = 0; ks < 2; ks++)
#pragma unroll
            for (int t = 0; t < 8; t++) {
                const float nkt = tanhf(nk[ks * 32 + quad * 8 + t]);
                pn[0] += (float)qf[0][ks][t] * nkt;
                pn[1] += (float)qf[1][ks][t] * nkt;
            }
#pragma unroll
        for (int rt = 0; rt < 2; rt++) {
            pn[rt] += __shfl_xor(pn[rt], 16);
            pn[rt] += __shfl_xor(pn[rt], 32);
            pnull[rt] = rowOk[rt] ? EXP2(pn[rt]) : 1.0f;
        }
    }
    float negsel[2];
#pragma unroll
    for (int rt = 0; rt < 2; rt++) {
        negsel[rt] = rowOk[rt] ? -1.0e30f : 0.0f;
        if (!rowOk[rt]) {
            const f16x8 zz = {(f16)0, (f16)0, (f16)0, (f16)0, (f16)0, (f16)0, (f16)0, (f16)0};
            qf[rt][0] = zz; qf[rt][1] = zz;   // dead rows: S contribution = 0
        }
    }

    f32x4 acc[2][4];   // [rt][ds]: row rt*16+quad*4+reg, col d = ds*16+l15
    f32x4 accl[2];     // row sums, same row layout
#pragma unroll
    for (int rt = 0; rt < 2; rt++)
#pragma unroll
        for (int reg = 0; reg < 4; reg++) {
            const float pr = __shfl(pnull[rt], quad * 4 + reg, 16);
            accl[rt][reg] = pr;
#pragma unroll
            for (int ds = 0; ds < 4; ds++)
                acc[rt][ds][reg] = pr * nv[ds * 16 + l15];
        }

    const f16* kg0 = kws + (size_t)bh * MM * DH;
    const f16* vg0 = vtws + (size_t)bh * DH * MM;
    const int sr = tid >> 2;          // 0..63
    const int sc = (tid & 3) * 16;    // 16-half chunk
    const f16x4 vone = {(f16)1, (f16)1, (f16)1, (f16)1};
    const int jbeg = jh << 10, jend = jbeg + 1024;

    for (int jc = jbeg; jc < jend; jc += 64) {
        uint4 kr0 = *(const uint4*)(kg0 + (size_t)(jc + sr) * DH + sc);
        uint4 kr1 = *(const uint4*)(kg0 + (size_t)(jc + sr) * DH + sc + 8);
        uint4 vr0 = *(const uint4*)(vg0 + (size_t)sr * MM + jc + sc);
        uint4 vr1 = *(const uint4*)(vg0 + (size_t)sr * MM + jc + sc + 8);
        int4 cmv[4];
#pragma unroll
        for (int jj = 0; jj < 4; jj++)
            cmv[jj] = *(const int4*)(cmask + (size_t)b * MM + jc + jj * 16 + quad * 4);

        __syncthreads();
        *(uint4*)(sK + sr * 72 + sc)     = kr0;
        *(uint4*)(sK + sr * 72 + sc + 8) = kr1;
        *(uint4*)(sV + sr * 72 + sc)     = vr0;
        *(uint4*)(sV + sr * 72 + sc + 8) = vr1;
        __syncthreads();

        // C-init: column mask (and dead-row override) folded into the MFMA
        f32x4 st[2][4];
#pragma unroll
        for (int rt = 0; rt < 2; rt++)
#pragma unroll
            for (int jj = 0; jj < 4; jj++) {
                st[rt][jj][0] = cmv[jj].x ? 0.0f : negsel[rt];
                st[rt][jj][1] = cmv[jj].y ? 0.0f : negsel[rt];
                st[rt][jj][2] = cmv[jj].z ? 0.0f : negsel[rt];
                st[rt][jj][3] = cmv[jj].w ? 0.0f : negsel[rt];
            }

        // S^T = K Q^T (C layout: j = quad*4+reg, r = l15); kb reused 2x
#pragma unroll
        for (int ks = 0; ks < 2; ks++) {
            f16x8 kb[4];
#pragma unroll
            for (int jj = 0; jj < 4; jj++)
                kb[jj] = *(const f16x8*)(sK + (jj * 16 + l15) * 72 + ks * 32 + quad * 8);
#pragma unroll
            for (int rt = 0; rt < 2; rt++)
#pragma unroll
                for (int jj = 0; jj < 4; jj++)
                    st[rt][jj] = __builtin_amdgcn_mfma_f32_16x16x32_f16(
                        kb[jj], qf[rt][ks], st[rt][jj], 0, 0, 0);
        }

        // p = exp2(st): masked cols -> 0, dead rows -> 1; stays in registers
        f16x4 pa[2][4];
#pragma unroll
        for (int rt = 0; rt < 2; rt++)
#pragma unroll
            for (int jj = 0; jj < 4; jj++)
                pa[rt][jj] = pk4(EXP2(st[rt][jj][0]), EXP2(st[rt][jj][1]),
                                 EXP2(st[rt][jj][2]), EXP2(st[rt][jj][3]));

        // O += P V ; denominator += P . ones  (vb reused 2x)
#pragma unroll
        for (int jj = 0; jj < 4; jj++) {
            f16x4 vb[4];
#pragma unroll
            for (int ds = 0; ds < 4; ds++)
                vb[ds] = *(const f16x4*)(sV + (ds * 16 + l15) * 72 + jj * 16 + quad * 4);
#pragma unroll
            for (int rt = 0; rt < 2; rt++) {
#pragma unroll
                for (int ds = 0; ds < 4; ds++)
                    acc[rt][ds] = __builtin_amdgcn_mfma_f32_16x16x16f16(
                        pa[rt][jj], vb[ds], acc[rt][ds], 0, 0, 0);
                accl[rt] = __builtin_amdgcn_mfma_f32_16x16x16f16(
                    pa[rt][jj], vone, accl[rt], 0, 0, 0);
            }
        }
    }

    // epilogue: raw partials (merge divides)
#pragma unroll
    for (int rt = 0; rt < 2; rt++)
#pragma unroll
        for (int ds = 0; ds < 4; ds++)
#pragma unroll
            for (int reg = 0; reg < 4; reg++) {
                const int r = q0 + rt * 16 + quad * 4 + reg;
                Op[((size_t)jh * 8192 + b * 2048 + r) * 512 + h * 64 + ds * 16 + l15] =
                    acc[rt][ds][reg];
            }
    if (l15 == 0) {
#pragma unroll
        for (int rt = 0; rt < 2; rt++)
#pragma unroll
            for (int reg = 0; reg < 4; reg++)
                lp[((size_t)jh * 32 + bh) * 2048 + q0 + rt * 16 + quad * 4 + reg] =
                    accl[rt][reg];
    }
}

// ---------------------------------------------------------------------------
// Merge j-halves: O = (O1+O2)/(l1+l2), bsplit -> oh/ol (bf16x2 A for mgemm2).
// ---------------------------------------------------------------------------
__global__ void merge_k(const float* __restrict__ Op, const float* __restrict__ lp,
                        ushort* __restrict__ oh, ushort* __restrict__ ol)
{
    const int i = blockIdx.x * 256 + threadIdx.x;   // 1,048,576 threads
    const int row = i >> 7;                          // 0..8191
    const int c4  = i & 127;
    const int b = row >> 11, n = row & 2047, h = c4 >> 4;
    const float l = lp[((size_t)b * 8 + h) * 2048 + n] +
                    lp[((size_t)32 + b * 8 + h) * 2048 + n];
    const float inv = 1.0f / l;
    const float4 o1 = *(const float4*)(Op + (size_t)row * 512 + c4 * 4);
    const float4 o2 = *(const float4*)(Op + (size_t)(8192 + row) * 512 + c4 * 4);
    float v[4] = {(o1.x + o2.x) * inv, (o1.y + o2.y) * inv,
                  (o1.z + o2.z) * inv, (o1.w + o2.w) * inv};
    ushort hh[4], ll[4];
#pragma unroll
    for (int j = 0; j < 4; j++) bsplit(v[j], hh[j], ll[j]);
    ushort4 H = {hh[0], hh[1], hh[2], hh[3]};
    ushort4 L = {ll[0], ll[1], ll[2], ll[3]};
    *(ushort4*)(oh + (size_t)row * 512 + c4 * 4) = H;
    *(ushort4*)(ol + (size_t)row * 512 + c4 * 4) = L;
}

// ---------------------------------------------------------------------------
// bf16x2-split MFMA GEMM for the final projection: out = O @ Wo + bias.
// ---------------------------------------------------------------------------
__launch_bounds__(256)
__global__ void mgemm2(const ushort* __restrict__ Ah, const ushort* __restrict__ Al,
                       const ushort* __restrict__ Bh, const ushort* __restrict__ Bl,
                       float* __restrict__ o32, const float* __restrict__ bias,
                       int K)
{
    __shared__ ushort sAh[128 * 36], sAl[128 * 36];
    __shared__ ushort sBh[64 * 36],  sBl[64 * 36];

    const int tid  = threadIdx.x;
    const int wave = tid >> 6, lane = tid & 63;
    const int l15  = lane & 15, quad = lane >> 4;
    const size_t r0 = (size_t)blockIdx.x * 128;
    const int c0 = blockIdx.y * 64;

    const int sr = tid >> 2;
    const int sc = (tid & 3) * 8;

    f32x4 acc[2][4] = {};

    for (int k0 = 0; k0 < K; k0 += 32) {
        uint4 ah0 = *(const uint4*)(Ah + (r0 + sr) * K + k0 + sc);
        uint4 ah1 = *(const uint4*)(Ah + (r0 + 64 + sr) * K + k0 + sc);
        uint4 al0 = *(const uint4*)(Al + (r0 + sr) * K + k0 + sc);
        uint4 al1 = *(const uint4*)(Al + (r0 + 64 + sr) * K + k0 + sc);
        uint4 bh  = *(const uint4*)(Bh + (size_t)(c0 + sr) * K + k0 + sc);
        uint4 bl  = *(const uint4*)(Bl + (size_t)(c0 + sr) * K + k0 + sc);
        __syncthreads();
        *(uint4*)(sAh + sr * 36 + sc)        = ah0;
        *(uint4*)(sAh + (64 + sr) * 36 + sc) = ah1;
        *(uint4*)(sAl + sr * 36 + sc)        = al0;
        *(uint4*)(sAl + (64 + sr) * 36 + sc) = al1;
        *(uint4*)(sBh + sr * 36 + sc)        = bh;
        *(uint4*)(sBl + sr * 36 + sc)        = bl;
        __syncthreads();

        bf16x8v a_h[2], a_l[2], b_h[4], b_l[4];
#pragma unroll
        for (int rt = 0; rt < 2; rt++) {
            const int r = wave * 32 + rt * 16 + l15;
            a_h[rt] = *(const bf16x8v*)(sAh + r * 36 + quad * 8);
            a_l[rt] = *(const bf16x8v*)(sAl + r * 36 + quad * 8);
        }
#pragma unroll
        for (int ct = 0; ct < 4; ct++) {
            const int c = ct * 16 + l15;
            b_h[ct] = *(const bf16x8v*)(sBh + c * 36 + quad * 8);
            b_l[ct] = *(const bf16x8v*)(sBl + c * 36 + quad * 8);
        }
#pragma unroll
        for (int rt = 0; rt < 2; rt++)
#pragma unroll
            for (int ct = 0; ct < 4; ct++) {
                acc[rt][ct] = __builtin_amdgcn_mfma_f32_16x16x32_bf16(a_h[rt], b_h[ct], acc[rt][ct], 0, 0, 0);
                acc[rt][ct] = __builtin_amdgcn_mfma_f32_16x16x32_bf16(a_h[rt], b_l[ct], acc[rt][ct], 0, 0, 0);
                acc[rt][ct] = __builtin_amdgcn_mfma_f32_16x16x32_bf16(a_l[rt], b_h[ct], acc[rt][ct], 0, 0, 0);
            }
    }

#pragma unroll
    for (int rt = 0; rt < 2; rt++)
#pragma unroll
        for (int ct = 0; ct < 4; ct++) {
            const int col = c0 + ct * 16 + l15;
            const float bv = bias[col];
#pragma unroll
            for (int reg = 0; reg < 4; reg++) {
                const size_t row = r0 + wave * 32 + rt * 16 + quad * 4 + reg;
                o32[row * 512 + col] = acc[rt][ct][reg] + bv;
            }
        }
}

extern "C" void kernel_launch(void* const* d_in, const int* in_sizes, int n_in,
                              void* d_out, int out_size, void* d_ws, size_t ws_size,
                              hipStream_t stream)
{
    const float* x    = (const float*)d_in[0];
    const float* ctx  = (const float*)d_in[1];
    const int*   mask = (const int*)d_in[2];
    const int*   cmsk = (const int*)d_in[3];
    const float* Wq   = (const float*)d_in[4];
    const float* Wkv  = (const float*)d_in[5];
    const float* Wo   = (const float*)d_in[6];
    const float* bo   = (const float*)d_in[7];
    const float* nk   = (const float*)d_in[8];
    const float* nv   = (const float*)d_in[9];
    float* out = (float*)d_out;

    const size_t S = (size_t)BB * HEADS * NN * DH;  // 4,194,304 elems

    f16* qws = (f16*)d_ws;                  // 8 MB
    f16* kws = qws + S;                     // 8 MB
    f16* vt  = kws + S;                     // 8 MB
    f16* wq16  = vt + S;                    // 0.5 MB
    f16* wkv16 = wq16 + 512 * 512;          // 1 MB
    ushort* woh = (ushort*)(wkv16 + 512 * 1024);   // 0.5 MB
    ushort* wol = woh + 512 * 512;                 // 0.5 MB
    float* lp = (float*)(wol + 512 * 512);         // 0.5 MB
    float* Op = lp + 2 * 32 * 2048;                // 32 MB
    // oh/ol alias qws/kws (dead after attn_k; merge_k writes them afterwards)
    ushort* oh = (ushort*)qws;
    ushort* ol = (ushort*)kws;

    wprep_k<<<512, 256, 0, stream>>>(Wq, Wkv, Wo, wq16, wkv16, woh, wol);
    proj_k<<<dim3(64, 24), 256, 0, stream>>>(x, ctx, wq16, wkv16, qws, kws, vt);
    attn_k<<<dim3(32, 16, 2), 256, 0, stream>>>(qws, kws, vt, mask, cmsk, nk, nv, Op, lp);
    merge_k<<<4096, 256, 0, stream>>>(Op, lp, oh, ol);
    mgemm2<<<dim3(64, 8), 256, 0, stream>>>(oh, ol, woh, wol, out, bo, 512);
}

// Round 10
// 199.879 us; speedup vs baseline: 1.6514x; 1.0255x over previous
//
#include <hip/hip_runtime.h>
#include <math.h>

#define BB 4
#define NN 2048
#define MM 2048
#define HEADS 8
#define DH 64

typedef _Float16 f16;
typedef _Float16 f16x4 __attribute__((ext_vector_type(4)));
typedef _Float16 f16x8 __attribute__((ext_vector_type(8)));
typedef float f32x4 __attribute__((ext_vector_type(4)));
typedef short bf16x8v __attribute__((ext_vector_type(8)));
typedef unsigned short ushort;

#define LOG2E 1.44269504088896f
#define QSCALE (0.125f * LOG2E)

#if __has_builtin(__builtin_amdgcn_exp2f)
#define EXP2(x) __builtin_amdgcn_exp2f(x)
#else
#define EXP2(x) exp2f(x)
#endif

__device__ __forceinline__ void bsplit(float v, ushort& h, ushort& l) {
    unsigned bits = __float_as_uint(v);
    float res = v - __uint_as_float(bits & 0xffff0000u);
    h = (ushort)(bits >> 16);
    l = (ushort)(__float_as_uint(res) >> 16);
}

__device__ __forceinline__ f16x4 pk4(float a, float b, float c, float d) {
#if __has_builtin(__builtin_amdgcn_cvt_pkrtz)
    auto t0 = __builtin_amdgcn_cvt_pkrtz(a, b);
    auto t1 = __builtin_amdgcn_cvt_pkrtz(c, d);
    f16x4 r;
    r[0] = t0[0]; r[1] = t0[1]; r[2] = t1[0]; r[3] = t1[1];
    return r;
#else
    f16x4 r = {(f16)a, (f16)b, (f16)c, (f16)d};
    return r;
#endif
}

// ---------------------------------------------------------------------------
// Fused weight prep (1 launch): Wq->[N][K]f16, Wkv->[N][K]f16, Wo->[N][K]
// bf16 hi/lo. 512 blocks: [0,128) Wq, [128,384) Wkv, [384,512) Wo.
// ---------------------------------------------------------------------------
__global__ void wprep_k(const float* __restrict__ Wq, const float* __restrict__ Wkv,
                        const float* __restrict__ Wo,
                        f16* __restrict__ wq16, f16* __restrict__ wkv16,
                        ushort* __restrict__ woh, ushort* __restrict__ wol)
{
    __shared__ ushort S0[64 * 36], S1[64 * 36];
    const int tid = threadIdx.x;
    const int bid = blockIdx.x;
    const int K = 512;
    const float* W; int N; f16* T16; ushort *Th, *Tl; int id;
    if (bid < 128)      { W = Wq;  N = 512;  T16 = wq16;  Th = 0; Tl = 0; id = bid; }
    else if (bid < 384) { W = Wkv; N = 1024; T16 = wkv16; Th = 0; Tl = 0; id = bid - 128; }
    else                { W = Wo;  N = 512;  T16 = 0; Th = woh; Tl = wol; id = bid - 384; }
    const int k0 = (id & 15) * 32, n0 = (id >> 4) * 64;
    const int kr = tid >> 3, nc = (tid & 7) * 8;
    float4 v0 = *(const float4*)(W + (size_t)(k0 + kr) * N + n0 + nc);
    float4 v1 = *(const float4*)(W + (size_t)(k0 + kr) * N + n0 + nc + 4);
    float e[8] = {v0.x, v0.y, v0.z, v0.w, v1.x, v1.y, v1.z, v1.w};
    const int n = tid >> 2, kc = (tid & 3) * 8;
    if (T16) {
        f16* Sf = (f16*)S0;
#pragma unroll
        for (int j = 0; j < 8; j++) Sf[(nc + j) * 36 + kr] = (f16)e[j];
        __syncthreads();
        *(uint4*)(T16 + (size_t)(n0 + n) * K + k0 + kc) = *(const uint4*)(Sf + n * 36 + kc);
    } else {
#pragma unroll
        for (int j = 0; j < 8; j++) {
            ushort h, l;
            bsplit(e[j], h, l);
            S0[(nc + j) * 36 + kr] = h;
            S1[(nc + j) * 36 + kr] = l;
        }
        __syncthreads();
        *(uint4*)(Th + (size_t)(n0 + n) * K + k0 + kc) = *(const uint4*)(S0 + n * 36 + kc);
        *(uint4*)(Tl + (size_t)(n0 + n) * K + k0 + kc) = *(const uint4*)(S1 + n * 36 + kc);
    }
}

// ---------------------------------------------------------------------------
// Fused projections v2: 128x128 tiles, grid (64, 12).
// by 0..3  : Q cols = tanh(x@Wq)*QSCALE   -> qws f16 [bh][n][d]
// by 4..11 : KV cols; kv<512: K=tanh -> kws; kv>=512: V -> vt [bh][d][m]
// A re-reads halved vs 64-col tiles; 16 MFMA per k-iter per wave.
// ---------------------------------------------------------------------------
__launch_bounds__(256)
__global__ void proj_k(const float* __restrict__ x, const float* __restrict__ ctx,
                       const f16* __restrict__ wq16, const f16* __restrict__ wkv16,
                       f16* __restrict__ qws, f16* __restrict__ kws, f16* __restrict__ vt)
{
    __shared__ f16 sA[128 * 36];
    __shared__ f16 sB[128 * 36];

    const int tid  = threadIdx.x;
    const int wave = tid >> 6, lane = tid & 63;
    const int l15  = lane & 15, quad = lane >> 4;
    const int by = blockIdx.y;
    const int isQ = (by < 4);
    const float* A = isQ ? x : ctx;
    const f16* Bt  = isQ ? wq16 : wkv16;
    const int c0 = (isQ ? by : by - 4) * 128;
    const size_t r0 = (size_t)blockIdx.x * 128;
    const int K = 512;

    const int ar = tid >> 1;           // 0..127
    const int ac = (tid & 1) * 16;     // 0 / 16

    f32x4 acc[2][8] = {};

    for (int k0 = 0; k0 < K; k0 += 32) {
        const float* ap = A + (r0 + ar) * K + k0 + ac;
        float4 a0 = *(const float4*)(ap + 0);
        float4 a1 = *(const float4*)(ap + 4);
        float4 a2 = *(const float4*)(ap + 8);
        float4 a3 = *(const float4*)(ap + 12);
        uint4 bv0 = *(const uint4*)(Bt + (size_t)(c0 + ar) * K + k0 + ac);
        uint4 bv1 = *(const uint4*)(Bt + (size_t)(c0 + ar) * K + k0 + ac + 8);
        f16x8 pa0, pa1;
        pa0[0] = (f16)a0.x; pa0[1] = (f16)a0.y; pa0[2] = (f16)a0.z; pa0[3] = (f16)a0.w;
        pa0[4] = (f16)a1.x; pa0[5] = (f16)a1.y; pa0[6] = (f16)a1.z; pa0[7] = (f16)a1.w;
        pa1[0] = (f16)a2.x; pa1[1] = (f16)a2.y; pa1[2] = (f16)a2.z; pa1[3] = (f16)a2.w;
        pa1[4] = (f16)a3.x; pa1[5] = (f16)a3.y; pa1[6] = (f16)a3.z; pa1[7] = (f16)a3.w;
        __syncthreads();
        *(f16x8*)(sA + ar * 36 + ac)     = pa0;
        *(f16x8*)(sA + ar * 36 + ac + 8) = pa1;
        *(uint4*)(sB + ar * 36 + ac)     = bv0;
        *(uint4*)(sB + ar * 36 + ac + 8) = bv1;
        __syncthreads();

        f16x8 a[2];
#pragma unroll
        for (int rt = 0; rt < 2; rt++)
            a[rt] = *(const f16x8*)(sA + (wave * 32 + rt * 16 + l15) * 36 + quad * 8);
#pragma unroll
        for (int half = 0; half < 2; half++) {
            f16x8 b[4];
#pragma unroll
            for (int c = 0; c < 4; c++)
                b[c] = *(const f16x8*)(sB + ((half * 4 + c) * 16 + l15) * 36 + quad * 8);
#pragma unroll
            for (int rt = 0; rt < 2; rt++)
#pragma unroll
                for (int c = 0; c < 4; c++)
                    acc[rt][half * 4 + c] = __builtin_amdgcn_mfma_f32_16x16x32_f16(
                        a[rt], b[c], acc[rt][half * 4 + c], 0, 0, 0);
        }
    }

    const int b    = (int)(r0 >> 11);
    const int rloc = ((int)(r0 & 2047)) + wave * 32;

#pragma unroll
    for (int rt = 0; rt < 2; rt++)
#pragma unroll
        for (int ct = 0; ct < 8; ct++) {
            const int col = c0 + ct * 16 + l15;     // 0..511 (Q) or 0..1023 (KV)
            if (isQ || col < 512) {                 // Q or K (tanh path)
                const int h = (col >> 6) & 7;
                const int d = col & 63;
                f16* dst = isQ ? qws : kws;
                const float sc = isQ ? QSCALE : 1.0f;
#pragma unroll
                for (int reg = 0; reg < 4; reg++) {
                    const int nn = rloc + rt * 16 + quad * 4 + reg;
                    dst[(((size_t)b * 8 + h) * 2048 + nn) * 64 + d] =
                        (f16)(tanhf(acc[rt][ct][reg]) * sc);
                }
            } else {                                // V, transposed
                const int c = col - 512;
                const int h = c >> 6;
                const int d = c & 63;
                const int m0 = rloc + rt * 16 + quad * 4;
                f16x4 pk;
#pragma unroll
                for (int reg = 0; reg < 4; reg++) pk[reg] = (f16)acc[rt][ct][reg];
                *(f16x4*)(vt + (((size_t)b * 8 + h) * 64 + d) * 2048 + m0) = pk;
            }
        }
}

// ---------------------------------------------------------------------------
// MFMA fp16 flash attention v6 (unchanged from round 9): 32 q-rows/wave,
// grid (32,16,2) j-split, fixed-shift exp2 softmax, mask in MFMA C-init,
// ones-column MFMA denominator. Split-merge exact: O = (O1+O2)/(l1+l2).
// ---------------------------------------------------------------------------
__launch_bounds__(256, 4)
__global__ void attn_k(const f16* __restrict__ qws, const f16* __restrict__ kws,
                       const f16* __restrict__ vtws,
                       const int* __restrict__ mask, const int* __restrict__ cmask,
                       const float* __restrict__ nk, const float* __restrict__ nv,
                       float* __restrict__ Op, float* __restrict__ lp)
{
    __shared__ f16 sK[64 * 72];      // [j][d]
    __shared__ f16 sV[64 * 72];      // [d][j]

    const int tid  = threadIdx.x;
    const int wave = tid >> 6, lane = tid & 63;
    const int l15  = lane & 15, quad = lane >> 4;
    const int bh = blockIdx.x, b = bh >> 3, h = bh & 7;
    const int q0 = blockIdx.y * 128 + wave * 32;
    const int jh = blockIdx.z;

    f16x8 qf[2][2];
    const f16* qbase = qws + ((size_t)bh * NN + q0) * DH;
#pragma unroll
    for (int rt = 0; rt < 2; rt++)
#pragma unroll
        for (int ks = 0; ks < 2; ks++)
            qf[rt][ks] = *(const f16x8*)(qbase + (rt * 16 + l15) * DH + ks * 32 + quad * 8);

    int rowOk[2];
#pragma unroll
    for (int rt = 0; rt < 2; rt++)
        rowOk[rt] = mask[(size_t)b * NN + q0 + rt * 16 + l15];

    float pnull[2] = {0.0f, 0.0f};
    if (jh == 0) {
        float pn[2] = {0.f, 0.f};
#pragma unroll
        for (int ks = 0; ks < 2; ks++)
#pragma unroll
            for (int t = 0; t < 8; t++) {
                const float nkt = tanhf(nk[ks * 32 + quad * 8 + t]);
                pn[0] += (float)qf[0][ks][t] * nkt;
                pn[1] += (float)qf[1][ks][t] * nkt;
            }
#pragma unroll
        for (int rt = 0; rt < 2; rt++) {
            pn[rt] += __shfl_xor(pn[rt], 16);
            pn[rt] += __shfl_xor(pn[rt], 32);
            pnull[rt] = rowOk[rt] ? EXP2(pn[rt]) : 1.0f;
        }
    }
    float negsel[2];
#pragma unroll
    for (int rt = 0; rt < 2; rt++) {
        negsel[rt] = rowOk[rt] ? -1.0e30f : 0.0f;
        if (!rowOk[rt]) {
            const f16x8 zz = {(f16)0, (f16)0, (f16)0, (f16)0, (f16)0, (f16)0, (f16)0, (f16)0};
            qf[rt][0] = zz; qf[rt][1] = zz;
        }
    }

    f32x4 acc[2][4];
    f32x4 accl[2];
#pragma unroll
    for (int rt = 0; rt < 2; rt++)
#pragma unroll
        for (int reg = 0; reg < 4; reg++) {
            const float pr = __shfl(pnull[rt], quad * 4 + reg, 16);
            accl[rt][reg] = pr;
#pragma unroll
            for (int ds = 0; ds < 4; ds++)
                acc[rt][ds][reg] = pr * nv[ds * 16 + l15];
        }

    const f16* kg0 = kws + (size_t)bh * MM * DH;
    const f16* vg0 = vtws + (size_t)bh * DH * MM;
    const int sr = tid >> 2;
    const int sc = (tid & 3) * 16;
    const f16x4 vone = {(f16)1, (f16)1, (f16)1, (f16)1};
    const int jbeg = jh << 10, jend = jbeg + 1024;

    for (int jc = jbeg; jc < jend; jc += 64) {
        uint4 kr0 = *(const uint4*)(kg0 + (size_t)(jc + sr) * DH + sc);
        uint4 kr1 = *(const uint4*)(kg0 + (size_t)(jc + sr) * DH + sc + 8);
        uint4 vr0 = *(const uint4*)(vg0 + (size_t)sr * MM + jc + sc);
        uint4 vr1 = *(const uint4*)(vg0 + (size_t)sr * MM + jc + sc + 8);
        int4 cmv[4];
#pragma unroll
        for (int jj = 0; jj < 4; jj++)
            cmv[jj] = *(const int4*)(cmask + (size_t)b * MM + jc + jj * 16 + quad * 4);

        __syncthreads();
        *(uint4*)(sK + sr * 72 + sc)     = kr0;
        *(uint4*)(sK + sr * 72 + sc + 8) = kr1;
        *(uint4*)(sV + sr * 72 + sc)     = vr0;
        *(uint4*)(sV + sr * 72 + sc + 8) = vr1;
        __syncthreads();

        f32x4 st[2][4];
#pragma unroll
        for (int rt = 0; rt < 2; rt++)
#pragma unroll
            for (int jj = 0; jj < 4; jj++) {
                st[rt][jj][0] = cmv[jj].x ? 0.0f : negsel[rt];
                st[rt][jj][1] = cmv[jj].y ? 0.0f : negsel[rt];
                st[rt][jj][2] = cmv[jj].z ? 0.0f : negsel[rt];
                st[rt][jj][3] = cmv[jj].w ? 0.0f : negsel[rt];
            }

#pragma unroll
        for (int ks = 0; ks < 2; ks++) {
            f16x8 kb[4];
#pragma unroll
            for (int jj = 0; jj < 4; jj++)
                kb[jj] = *(const f16x8*)(sK + (jj * 16 + l15) * 72 + ks * 32 + quad * 8);
#pragma unroll
            for (int rt = 0; rt < 2; rt++)
#pragma unroll
                for (int jj = 0; jj < 4; jj++)
                    st[rt][jj] = __builtin_amdgcn_mfma_f32_16x16x32_f16(
                        kb[jj], qf[rt][ks], st[rt][jj], 0, 0, 0);
        }

        f16x4 pa[2][4];
#pragma unroll
        for (int rt = 0; rt < 2; rt++)
#pragma unroll
            for (int jj = 0; jj < 4; jj++)
                pa[rt][jj] = pk4(EXP2(st[rt][jj][0]), EXP2(st[rt][jj][1]),
                                 EXP2(st[rt][jj][2]), EXP2(st[rt][jj][3]));

#pragma unroll
        for (int jj = 0; jj < 4; jj++) {
            f16x4 vb[4];
#pragma unroll
            for (int ds = 0; ds < 4; ds++)
                vb[ds] = *(const f16x4*)(sV + (ds * 16 + l15) * 72 + jj * 16 + quad * 4);
#pragma unroll
            for (int rt = 0; rt < 2; rt++) {
#pragma unroll
                for (int ds = 0; ds < 4; ds++)
                    acc[rt][ds] = __builtin_amdgcn_mfma_f32_16x16x16f16(
                        pa[rt][jj], vb[ds], acc[rt][ds], 0, 0, 0);
                accl[rt] = __builtin_amdgcn_mfma_f32_16x16x16f16(
                    pa[rt][jj], vone, accl[rt], 0, 0, 0);
            }
        }
    }

#pragma unroll
    for (int rt = 0; rt < 2; rt++)
#pragma unroll
        for (int ds = 0; ds < 4; ds++)
#pragma unroll
            for (int reg = 0; reg < 4; reg++) {
                const int r = q0 + rt * 16 + quad * 4 + reg;
                Op[((size_t)jh * 8192 + b * 2048 + r) * 512 + h * 64 + ds * 16 + l15] =
                    acc[rt][ds][reg];
            }
    if (l15 == 0) {
#pragma unroll
        for (int rt = 0; rt < 2; rt++)
#pragma unroll
            for (int reg = 0; reg < 4; reg++)
                lp[((size_t)jh * 32 + bh) * 2048 + q0 + rt * 16 + quad * 4 + reg] =
                    accl[rt][reg];
    }
}

// ---------------------------------------------------------------------------
// Merge j-halves: O = (O1+O2)/(l1+l2), bsplit -> oh/ol (bf16x2 A for mgemm2).
// ---------------------------------------------------------------------------
__global__ void merge_k(const float* __restrict__ Op, const float* __restrict__ lp,
                        ushort* __restrict__ oh, ushort* __restrict__ ol)
{
    const int i = blockIdx.x * 256 + threadIdx.x;
    const int row = i >> 7;
    const int c4  = i & 127;
    const int b = row >> 11, n = row & 2047, h = c4 >> 4;
    const float l = lp[((size_t)b * 8 + h) * 2048 + n] +
                    lp[((size_t)32 + b * 8 + h) * 2048 + n];
    const float inv = 1.0f / l;
    const float4 o1 = *(const float4*)(Op + (size_t)row * 512 + c4 * 4);
    const float4 o2 = *(const float4*)(Op + (size_t)(8192 + row) * 512 + c4 * 4);
    float v[4] = {(o1.x + o2.x) * inv, (o1.y + o2.y) * inv,
                  (o1.z + o2.z) * inv, (o1.w + o2.w) * inv};
    ushort hh[4], ll[4];
#pragma unroll
    for (int j = 0; j < 4; j++) bsplit(v[j], hh[j], ll[j]);
    ushort4 H = {hh[0], hh[1], hh[2], hh[3]};
    ushort4 L = {ll[0], ll[1], ll[2], ll[3]};
    *(ushort4*)(oh + (size_t)row * 512 + c4 * 4) = H;
    *(ushort4*)(ol + (size_t)row * 512 + c4 * 4) = L;
}

// ---------------------------------------------------------------------------
// bf16x2-split MFMA GEMM for the final projection: out = O @ Wo + bias.
// ---------------------------------------------------------------------------
__launch_bounds__(256)
__global__ void mgemm2(const ushort* __restrict__ Ah, const ushort* __restrict__ Al,
                       const ushort* __restrict__ Bh, const ushort* __restrict__ Bl,
                       float* __restrict__ o32, const float* __restrict__ bias,
                       int K)
{
    __shared__ ushort sAh[128 * 36], sAl[128 * 36];
    __shared__ ushort sBh[64 * 36],  sBl[64 * 36];

    const int tid  = threadIdx.x;
    const int wave = tid >> 6, lane = tid & 63;
    const int l15  = lane & 15, quad = lane >> 4;
    const size_t r0 = (size_t)blockIdx.x * 128;
    const int c0 = blockIdx.y * 64;

    const int sr = tid >> 2;
    const int sc = (tid & 3) * 8;

    f32x4 acc[2][4] = {};

    for (int k0 = 0; k0 < K; k0 += 32) {
        uint4 ah0 = *(const uint4*)(Ah + (r0 + sr) * K + k0 + sc);
        uint4 ah1 = *(const uint4*)(Ah + (r0 + 64 + sr) * K + k0 + sc);
        uint4 al0 = *(const uint4*)(Al + (r0 + sr) * K + k0 + sc);
        uint4 al1 = *(const uint4*)(Al + (r0 + 64 + sr) * K + k0 + sc);
        uint4 bh  = *(const uint4*)(Bh + (size_t)(c0 + sr) * K + k0 + sc);
        uint4 bl  = *(const uint4*)(Bl + (size_t)(c0 + sr) * K + k0 + sc);
        __syncthreads();
        *(uint4*)(sAh + sr * 36 + sc)        = ah0;
        *(uint4*)(sAh + (64 + sr) * 36 + sc) = ah1;
        *(uint4*)(sAl + sr * 36 + sc)        = al0;
        *(uint4*)(sAl + (64 + sr) * 36 + sc) = al1;
        *(uint4*)(sBh + sr * 36 + sc)        = bh;
        *(uint4*)(sBl + sr * 36 + sc)        = bl;
        __syncthreads();

        bf16x8v a_h[2], a_l[2], b_h[4], b_l[4];
#pragma unroll
        for (int rt = 0; rt < 2; rt++) {
            const int r = wave * 32 + rt * 16 + l15;
            a_h[rt] = *(const bf16x8v*)(sAh + r * 36 + quad * 8);
            a_l[rt] = *(const bf16x8v*)(sAl + r * 36 + quad * 8);
        }
#pragma unroll
        for (int ct = 0; ct < 4; ct++) {
            const int c = ct * 16 + l15;
            b_h[ct] = *(const bf16x8v*)(sBh + c * 36 + quad * 8);
            b_l[ct] = *(const bf16x8v*)(sBl + c * 36 + quad * 8);
        }
#pragma unroll
        for (int rt = 0; rt < 2; rt++)
#pragma unroll
            for (int ct = 0; ct < 4; ct++) {
                acc[rt][ct] = __builtin_amdgcn_mfma_f32_16x16x32_bf16(a_h[rt], b_h[ct], acc[rt][ct], 0, 0, 0);
                acc[rt][ct] = __builtin_amdgcn_mfma_f32_16x16x32_bf16(a_h[rt], b_l[ct], acc[rt][ct], 0, 0, 0);
                acc[rt][ct] = __builtin_amdgcn_mfma_f32_16x16x32_bf16(a_l[rt], b_h[ct], acc[rt][ct], 0, 0, 0);
            }
    }

#pragma unroll
    for (int rt = 0; rt < 2; rt++)
#pragma unroll
        for (int ct = 0; ct < 4; ct++) {
            const int col = c0 + ct * 16 + l15;
            const float bv = bias[col];
#pragma unroll
            for (int reg = 0; reg < 4; reg++) {
                const size_t row = r0 + wave * 32 + rt * 16 + quad * 4 + reg;
                o32[row * 512 + col] = acc[rt][ct][reg] + bv;
            }
        }
}

extern "C" void kernel_launch(void* const* d_in, const int* in_sizes, int n_in,
                              void* d_out, int out_size, void* d_ws, size_t ws_size,
                              hipStream_t stream)
{
    const float* x    = (const float*)d_in[0];
    const float* ctx  = (const float*)d_in[1];
    const int*   mask = (const int*)d_in[2];
    const int*   cmsk = (const int*)d_in[3];
    const float* Wq   = (const float*)d_in[4];
    const float* Wkv  = (const float*)d_in[5];
    const float* Wo   = (const float*)d_in[6];
    const float* bo   = (const float*)d_in[7];
    const float* nk   = (const float*)d_in[8];
    const float* nv   = (const float*)d_in[9];
    float* out = (float*)d_out;

    const size_t S = (size_t)BB * HEADS * NN * DH;  // 4,194,304 elems

    f16* qws = (f16*)d_ws;                  // 8 MB
    f16* kws = qws + S;                     // 8 MB
    f16* vt  = kws + S;                     // 8 MB
    f16* wq16  = vt + S;                    // 0.5 MB
    f16* wkv16 = wq16 + 512 * 512;          // 1 MB
    ushort* woh = (ushort*)(wkv16 + 512 * 1024);   // 0.5 MB
    ushort* wol = woh + 512 * 512;                 // 0.5 MB
    float* lp = (float*)(wol + 512 * 512);         // 0.5 MB
    float* Op = lp + 2 * 32 * 2048;                // 32 MB
    ushort* oh = (ushort*)qws;              // alias (dead after attn_k)
    ushort* ol = (ushort*)kws;

    wprep_k<<<512, 256, 0, stream>>>(Wq, Wkv, Wo, wq16, wkv16, woh, wol);
    proj_k<<<dim3(64, 12), 256, 0, stream>>>(x, ctx, wq16, wkv16, qws, kws, vt);
    attn_k<<<dim3(32, 16, 2), 256, 0, stream>>>(qws, kws, vt, mask, cmsk, nk, nv, Op, lp);
    merge_k<<<4096, 256, 0, stream>>>(Op, lp, oh, ol);
    mgemm2<<<dim3(64, 8), 256, 0, stream>>>(oh, ol, woh, wol, out, bo, 512);
}